// Round 1
// 1085.233 us; speedup vs baseline: 1.0593x; 1.0593x over previous
//
// HNHN layer on MI355X (gfx950). Round 3: bit-packed incidence matrix.
// B1 is binary -> pack to 1 bit/entry (16 MB) in K1 (rowsum = popcount),
// bit-transpose once (K1b), and MM1/MM2 expand 1 byte/thread/iter to bf16
// directly into the (already conflict-free-swizzled) a_lds layout.
// Kills 2 of the 3 512 MB fp32 reads of B1 (~1 GB HBM saved) and removes
// the fat strided A-load chain from the MM K-loops.
// Pipeline:
//   K0:  W0,W1 -> bf16 transposed (W0T/W1T, [n][k])
//   K1:  pack B1 rows -> pk1[n][256 u32] (LSB-first) + node_card = popcnt^-0.5
//   K1b: bit-transpose pk1 -> pk1T[e][512 u32] (bit r of word w = node w*32+r)
//   K2:  y0 = x0@W0 (MFMA); epilogue: y0sT[c][n] = bf16(node_card[n]*y0[n,c])
//   K2b: y0sT aux rows: 256=node_card, 257=1.0, 258..271=0
//   MM1: mm1p[sp] = B1^T-slice @ y0s (split-K=8; A from pk1T bytes)
//   K3:  x1 = d1inv*sum(p)+b01; out1=relu(x1); x1bf=bf16(x1); edge_card=colsum^-1.5
//   K5:  y1 = x1@W1 (MFMA); epilogue y1sT[c][e]=bf16(edge_card[e]*y1)
//   K5b: y1sT aux rows
//   MM2: mm2p[sp] = B1-slice @ y1s (split-K=4; A from pk1 bytes)
//   K6:  out0 = relu(sum(mm2p)/sum(d0p) + b10)
#include <hip/hip_runtime.h>
#include <stdint.h>

#define NN 16384
#define NE 8192
#define CH 256
#define MM1_SPLIT 8
#define MM2_SPLIT 4

typedef __attribute__((ext_vector_type(8))) short bf16x8;
typedef __attribute__((ext_vector_type(4))) float f32x4;

__device__ __forceinline__ unsigned short f2bf(float f) {  // RNE fp32->bf16
  unsigned u = __float_as_uint(f);
  u += 0x7FFFu + ((u >> 16) & 1u);
  return (unsigned short)(u >> 16);
}
__device__ __forceinline__ void async_copy16(const void* gptr, void* lptr) {
  __builtin_amdgcn_global_load_lds((const __attribute__((address_space(1))) unsigned int*)gptr,
                                   (__attribute__((address_space(3))) unsigned int*)lptr,
                                   16, 0, 0);
}

// LSB-first 32x32 bit transpose: result x'[k] bit j == input x[j] bit k.
// (Mirrored Hacker's Delight network: HD's original is MSB-first.)
__device__ __forceinline__ void transpose32(unsigned* x) {
  const unsigned masks[5] = {0x0000FFFFu, 0x00FF00FFu, 0x0F0F0F0Fu, 0x33333333u, 0x55555555u};
#pragma unroll
  for (int jj = 0; jj < 5; ++jj) {
    const int j = 16 >> jj;
    const unsigned m = masks[jj];
#pragma unroll
    for (int k = 0; k < 32; ++k) {
      if ((k & j) == 0) {
        unsigned t = ((x[k] >> j) ^ x[k + j]) & m;
        x[k] ^= (t << j);
        x[k + j] ^= t;
      }
    }
  }
}

// ---------------- K0: weight transpose to bf16 ----------------
__global__ void k0_transpose_w(const float* __restrict__ W0, const float* __restrict__ W1,
                               unsigned short* __restrict__ W0T, unsigned short* __restrict__ W1T) {
  const float* W = blockIdx.y ? W1 : W0;
  unsigned short* WT = blockIdx.y ? W1T : W0T;
  int n = blockIdx.x;
  int k = threadIdx.x;
  WT[n * CH + k] = f2bf(W[k * CH + n]);
}

// ---------------- K1: pack B1 row to bits + node_card ----------------
// Thread t owns 32 consecutive e (one u32 word, LSB-first: bit b <-> e = t*32+b).
// B1 entries are exactly 0.0f/1.0f -> bit = (floatbits >> 23) & 1.
__global__ void k1_pack_card(const float* __restrict__ B1, unsigned* __restrict__ pk1,
                             float* __restrict__ node_card) {
  int n = blockIdx.x;
  int t = threadIdx.x;
  const float4* p = (const float4*)(B1 + (size_t)n * NE + t * 32);
  unsigned w = 0;
#pragma unroll
  for (int jj = 0; jj < 8; ++jj) {
    float4 v = p[jj];
    w |= ((__float_as_uint(v.x) >> 23) & 1u) << (4 * jj);
    w |= ((__float_as_uint(v.y) >> 23) & 1u) << (4 * jj + 1);
    w |= ((__float_as_uint(v.z) >> 23) & 1u) << (4 * jj + 2);
    w |= ((__float_as_uint(v.w) >> 23) & 1u) << (4 * jj + 3);
  }
  pk1[(size_t)n * 256 + t] = w;
  int s = __popc(w);
  __shared__ int red[4];
#pragma unroll
  for (int off = 32; off; off >>= 1) s += __shfl_down(s, off, 64);
  if ((t & 63) == 0) red[t >> 6] = s;
  __syncthreads();
  if (t == 0) {
    float tot = (float)(red[0] + red[1] + red[2] + red[3]);
    node_card[n] = rsqrtf(tot);
  }
}

// ---------------- K1b: bit transpose pk1 -> pk1T ----------------
// pk1T[e][w] bit r = B1[w*32+r][e]. Reads scattered 8B/row (LLC absorbs:
// 16 MB unique, lines shared across co-resident blocks); writes coalesced.
__global__ __launch_bounds__(256) void k1b_bitT(const unsigned* __restrict__ pk1,
                                                unsigned* __restrict__ pk1T) {
  int bw = blockIdx.x & 127;   // e-word pair: words 2bw, 2bw+1 (e-range 64)
  int half = blockIdx.x >> 7;  // which half of the 512 n-tiles
  int t = threadIdx.x;
  int nt = half * 256 + t;     // n-word tile 0..511
  unsigned x0[32], x1[32];
#pragma unroll
  for (int r = 0; r < 32; ++r) {
    uint2 v = *(const uint2*)&pk1[(size_t)(nt * 32 + r) * 256 + 2 * bw];
    x0[r] = v.x;
    x1[r] = v.y;
  }
  transpose32(x0);
  transpose32(x1);
  int e0 = bw * 64;
#pragma unroll
  for (int c = 0; c < 32; ++c) {
    pk1T[(size_t)(e0 + c) * 512 + nt] = x0[c];
    pk1T[(size_t)(e0 + 32 + c) * 512 + nt] = x1[c];
  }
}

// ---------------- K2: y0 GEMM + scaled transpose epilogue ----------------
__global__ __launch_bounds__(256) void k2_y0(const float* __restrict__ X0,
                                             const unsigned short* __restrict__ W0T,
                                             const float* __restrict__ node_card,
                                             unsigned short* __restrict__ y0sT) {
  __shared__ __align__(16) unsigned short a_lds[64 * 32];
  __shared__ __align__(16) unsigned short b_lds[256 * 32];
  const int tid = threadIdx.x;
  const int wave = tid >> 6, lane = tid & 63;
  const int quad = lane >> 4, l15 = lane & 15;
  const int m0 = blockIdx.x * 64;
  const int ar = tid >> 3, ac = (tid & 7) * 4;

  f32x4 acc[4][4];
  const f32x4 fz = {0.f, 0.f, 0.f, 0.f};
#pragma unroll
  for (int i = 0; i < 4; ++i)
#pragma unroll
    for (int j = 0; j < 4; ++j) acc[i][j] = fz;

  for (int k0 = 0; k0 < CH; k0 += 32) {
    __syncthreads();
#pragma unroll
    for (int p = 0; p < 2; ++p) {
      float4 v = *(const float4*)(X0 + (size_t)(m0 + ar + p * 32) * CH + k0 + ac);
      uint2 w;
      w.x = ((unsigned)f2bf(v.x)) | ((unsigned)f2bf(v.y) << 16);
      w.y = ((unsigned)f2bf(v.z)) | ((unsigned)f2bf(v.w) << 16);
      *(uint2*)&a_lds[(ar + p * 32) * 32 + ac] = w;
    }
#pragma unroll
    for (int i = 0; i < 4; ++i) {
      int rowbase = wave * 64 + i * 16;
      const unsigned short* g = W0T + (size_t)(rowbase + (lane >> 2)) * CH + k0 + (lane & 3) * 8;
      async_copy16(g, &b_lds[rowbase * 32]);
    }
    __syncthreads();
    bf16x8 af[4];
#pragma unroll
    for (int i = 0; i < 4; ++i)
      af[i] = *(const bf16x8*)&a_lds[(i * 16 + l15) * 32 + quad * 8];
#pragma unroll
    for (int j = 0; j < 4; ++j) {
      bf16x8 bfr = *(const bf16x8*)&b_lds[(wave * 64 + j * 16 + l15) * 32 + quad * 8];
#pragma unroll
      for (int i = 0; i < 4; ++i)
        acc[i][j] = __builtin_amdgcn_mfma_f32_16x16x32_bf16(af[i], bfr, acc[i][j], 0, 0, 0);
    }
  }
#pragma unroll
  for (int i = 0; i < 4; ++i) {
    int row4 = m0 + i * 16 + quad * 4;
    float4 nc = *(const float4*)(node_card + row4);
#pragma unroll
    for (int j = 0; j < 4; ++j) {
      int col = wave * 64 + j * 16 + l15;
      f32x4 v = acc[i][j];
      ushort4 o;
      o.x = f2bf(v[0] * nc.x);
      o.y = f2bf(v[1] * nc.y);
      o.z = f2bf(v[2] * nc.z);
      o.w = f2bf(v[3] * nc.w);
      *(ushort4*)&y0sT[(size_t)col * NN + row4] = o;
    }
  }
}

// ---------------- K2b: y0sT aux rows ----------------
__global__ void k2b_aux(const float* __restrict__ node_card, unsigned short* __restrict__ y0sT) {
  int n = blockIdx.x * 256 + threadIdx.x;
  y0sT[(size_t)256 * NN + n] = f2bf(node_card[n]);
  y0sT[(size_t)257 * NN + n] = 0x3F80;  // 1.0 bf16
#pragma unroll
  for (int r = 258; r < 272; ++r) y0sT[(size_t)r * NN + n] = 0;
}

// ---------------- MM1: B1^T @ y0s (split-K=8, A from pk1T bytes) ----------
// a_lds row stride 40 shorts; write b128 at group kg ^ ((m>>4)&3) -- exactly
// mirrors the af[] read pattern, so it inherits its conflict-freedom.
__global__ __launch_bounds__(256) void mm1_kernel(const unsigned char* __restrict__ pk1T,
                                                  const unsigned short* __restrict__ y0sT,
                                                  float* __restrict__ mm1p,
                                                  float* __restrict__ auxD,
                                                  float* __restrict__ auxC) {
  __shared__ __align__(16) unsigned short a_lds[64 * 40];
  __shared__ __align__(16) unsigned short b_lds[272 * 32];
  const int tid = threadIdx.x;
  const int wave = tid >> 6, lane = tid & 63;
  const int quad = lane >> 4, l15 = lane & 15;
  const int m0 = blockIdx.x * 64;  // e-range
  const int sp = blockIdx.y;
  const int KS = NN / MM1_SPLIT;   // 2048
  const int kbase = sp * KS;

  const int am = tid >> 2;                  // e-row within tile (0..63)
  const int akg = tid & 3;                  // logical k-group (8 bf16 = 1 byte)
  const int ajbs = akg ^ ((am >> 4) & 3);   // swizzled physical group
  unsigned short* aw_dst = &a_lds[am * 40 + ajbs * 8];

  f32x4 acc[4][4];
  f32x4 acc5[4];
  const f32x4 fz = {0.f, 0.f, 0.f, 0.f};
#pragma unroll
  for (int i = 0; i < 4; ++i) {
    acc5[i] = fz;
#pragma unroll
    for (int j = 0; j < 4; ++j) acc[i][j] = fz;
  }

  const unsigned char* agp = pk1T + (size_t)(m0 + am) * (NN / 8) + (kbase >> 3) + akg;
  unsigned abyte = *agp;  // prefetched A byte (8 k-bits for row am)

  for (int kk = 0; kk < KS; kk += 32) {
    const int k0 = kbase + kk;
    __syncthreads();
    {  // expand 8 bits -> 8 bf16 {0,1} along k, single b128 LDS write
      uint4 aw;
#pragma unroll
      for (int j = 0; j < 4; ++j) {
        unsigned lo = (abyte >> (2 * j)) & 1u;
        unsigned hi = (abyte >> (2 * j + 1)) & 1u;
        ((unsigned*)&aw)[j] = lo * 0x3F80u + hi * 0x3F800000u;
      }
      *(uint4*)aw_dst = aw;
    }
    // B stage (global_load_lds, 16B/lane)
#pragma unroll
    for (int i = 0; i < 4; ++i) {
      int rowbase = wave * 64 + i * 16;
      const unsigned short* g = y0sT + (size_t)(rowbase + (lane >> 2)) * NN + k0 + (lane & 3) * 8;
      async_copy16(g, &b_lds[rowbase * 32]);
    }
    if (wave == 3) {
      const unsigned short* g = y0sT + (size_t)(256 + (lane >> 2)) * NN + k0 + (lane & 3) * 8;
      async_copy16(g, &b_lds[256 * 32]);
    }
    __syncthreads();
    // Prefetch next iteration's A byte (overlaps MFMA phase; uniform branch)
    if (kk + 32 < KS) {
      agp += 4;
      abyte = *agp;
    }
    bf16x8 af[4];
#pragma unroll
    for (int i = 0; i < 4; ++i) {
      int m = i * 16 + l15;
      int jbs = quad ^ ((m >> 4) & 3);  // = quad ^ i
      af[i] = *(const bf16x8*)&a_lds[m * 40 + jbs * 8];
    }
#pragma unroll
    for (int j = 0; j < 4; ++j) {
      bf16x8 bfr = *(const bf16x8*)&b_lds[(wave * 64 + j * 16 + l15) * 32 + quad * 8];
#pragma unroll
      for (int i = 0; i < 4; ++i)
        acc[i][j] = __builtin_amdgcn_mfma_f32_16x16x32_bf16(af[i], bfr, acc[i][j], 0, 0, 0);
    }
    if (wave == 3) {
      bf16x8 bfr = *(const bf16x8*)&b_lds[(256 + l15) * 32 + quad * 8];
#pragma unroll
      for (int i = 0; i < 4; ++i)
        acc5[i] = __builtin_amdgcn_mfma_f32_16x16x32_bf16(af[i], bfr, acc5[i], 0, 0, 0);
    }
  }
  float* outp = mm1p + (size_t)sp * NE * CH;
#pragma unroll
  for (int i = 0; i < 4; ++i) {
    int row4 = m0 + i * 16 + quad * 4;
#pragma unroll
    for (int j = 0; j < 4; ++j) {
      int col = wave * 64 + j * 16 + l15;
#pragma unroll
      for (int r = 0; r < 4; ++r) outp[(size_t)(row4 + r) * CH + col] = acc[i][j][r];
    }
  }
  if (wave == 3 && l15 < 2) {
    float* dst = (l15 == 0 ? auxD : auxC) + (size_t)sp * NE;
#pragma unroll
    for (int i = 0; i < 4; ++i) {
      int row4 = m0 + i * 16 + quad * 4;
#pragma unroll
      for (int r = 0; r < 4; ++r) dst[row4 + r] = acc5[i][r];
    }
  }
}

// ---------------- K3: edge finalize (reduce 8 partials) ----------------
__global__ void k3_edge_final(const float* __restrict__ mm1p, const float* __restrict__ auxD,
                              const float* __restrict__ auxC, const float* __restrict__ b01,
                              float* __restrict__ out1, unsigned short* __restrict__ x1bf,
                              float* __restrict__ edge_card) {
  int e = blockIdx.x, c = threadIdx.x;
  float ds = 0.f, p = 0.f;
#pragma unroll
  for (int sp = 0; sp < MM1_SPLIT; ++sp) {
    ds += auxD[(size_t)sp * NE + e];
    p += mm1p[(size_t)sp * NE * CH + (size_t)e * CH + c];
  }
  float x1 = p / ds + b01[c];
  out1[(size_t)e * CH + c] = fmaxf(x1, 0.f);
  x1bf[(size_t)e * CH + c] = f2bf(x1);
  if (c == 0) {
    float cs = 0.f;
#pragma unroll
    for (int sp = 0; sp < MM1_SPLIT; ++sp) cs += auxC[(size_t)sp * NE + e];
    edge_card[e] = 1.0f / (cs * sqrtf(cs));
  }
}

// ---------------- K5: y1 GEMM + scaled transpose epilogue ----------------
__global__ __launch_bounds__(256) void k5_y1(const unsigned short* __restrict__ x1bf,
                                             const unsigned short* __restrict__ W1T,
                                             const float* __restrict__ edge_card,
                                             unsigned short* __restrict__ y1sT) {
  __shared__ __align__(16) unsigned short a_lds[64 * 32];
  __shared__ __align__(16) unsigned short b_lds[256 * 32];
  const int tid = threadIdx.x;
  const int wave = tid >> 6, lane = tid & 63;
  const int quad = lane >> 4, l15 = lane & 15;
  const int m0 = blockIdx.x * 64;  // e-range

  f32x4 acc[4][4];
  const f32x4 fz = {0.f, 0.f, 0.f, 0.f};
#pragma unroll
  for (int i = 0; i < 4; ++i)
#pragma unroll
    for (int j = 0; j < 4; ++j) acc[i][j] = fz;

  for (int k0 = 0; k0 < CH; k0 += 32) {
    __syncthreads();
    {  // A: bf16 already, async copy. 16 rows per wave.
      const unsigned short* g = x1bf + (size_t)(m0 + wave * 16 + (lane >> 2)) * CH + k0 + (lane & 3) * 8;
      async_copy16(g, &a_lds[(wave * 16) * 32]);
    }
#pragma unroll
    for (int i = 0; i < 4; ++i) {
      int rowbase = wave * 64 + i * 16;
      const unsigned short* g = W1T + (size_t)(rowbase + (lane >> 2)) * CH + k0 + (lane & 3) * 8;
      async_copy16(g, &b_lds[rowbase * 32]);
    }
    __syncthreads();
    bf16x8 af[4];
#pragma unroll
    for (int i = 0; i < 4; ++i)
      af[i] = *(const bf16x8*)&a_lds[(i * 16 + l15) * 32 + quad * 8];
#pragma unroll
    for (int j = 0; j < 4; ++j) {
      bf16x8 bfr = *(const bf16x8*)&b_lds[(wave * 64 + j * 16 + l15) * 32 + quad * 8];
#pragma unroll
      for (int i = 0; i < 4; ++i)
        acc[i][j] = __builtin_amdgcn_mfma_f32_16x16x32_bf16(af[i], bfr, acc[i][j], 0, 0, 0);
    }
  }
#pragma unroll
  for (int i = 0; i < 4; ++i) {
    int row4 = m0 + i * 16 + quad * 4;
    float4 ec = *(const float4*)(edge_card + row4);
#pragma unroll
    for (int j = 0; j < 4; ++j) {
      int col = wave * 64 + j * 16 + l15;
      f32x4 v = acc[i][j];
      ushort4 o;
      o.x = f2bf(v[0] * ec.x);
      o.y = f2bf(v[1] * ec.y);
      o.z = f2bf(v[2] * ec.z);
      o.w = f2bf(v[3] * ec.w);
      *(ushort4*)&y1sT[(size_t)col * NE + row4] = o;
    }
  }
}

// ---------------- K5b: y1sT aux rows ----------------
__global__ void k5b_aux(const float* __restrict__ edge_card, unsigned short* __restrict__ y1sT) {
  int e = blockIdx.x * 256 + threadIdx.x;
  y1sT[(size_t)256 * NE + e] = f2bf(edge_card[e]);
#pragma unroll
  for (int r = 257; r < 272; ++r) y1sT[(size_t)r * NE + e] = 0;
}

// ---------------- MM2: B1 @ y1s (split-K=4, A from pk1 bytes) -------------
__global__ __launch_bounds__(256) void mm2_kernel(const unsigned char* __restrict__ pk1,
                                                  const unsigned short* __restrict__ y1sT,
                                                  float* __restrict__ mm2p,
                                                  float* __restrict__ d0p) {
  __shared__ __align__(16) unsigned short a_lds[64 * 40];
  __shared__ __align__(16) unsigned short b_lds[272 * 32];
  const int tid = threadIdx.x;
  const int wave = tid >> 6, lane = tid & 63;
  const int quad = lane >> 4, l15 = lane & 15;
  const int m0 = blockIdx.x * 64;  // node-range
  const int sp = blockIdx.y;
  const int KS = NE / MM2_SPLIT;   // 2048
  const int kbase = sp * KS;

  const int am = tid >> 2;   // node-row within tile
  const int akg = tid & 3;   // k-group; read pattern is unswizzled here
  unsigned short* aw_dst = &a_lds[am * 40 + akg * 8];

  f32x4 acc[4][4];
  f32x4 acc5[4];
  const f32x4 fz = {0.f, 0.f, 0.f, 0.f};
#pragma unroll
  for (int i = 0; i < 4; ++i) {
    acc5[i] = fz;
#pragma unroll
    for (int j = 0; j < 4; ++j) acc[i][j] = fz;
  }

  const unsigned char* agp = pk1 + (size_t)(m0 + am) * (NE / 8) + (kbase >> 3) + akg;
  unsigned abyte = *agp;

  for (int kk = 0; kk < KS; kk += 32) {
    const int k0 = kbase + kk;
    __syncthreads();
    {
      uint4 aw;
#pragma unroll
      for (int j = 0; j < 4; ++j) {
        unsigned lo = (abyte >> (2 * j)) & 1u;
        unsigned hi = (abyte >> (2 * j + 1)) & 1u;
        ((unsigned*)&aw)[j] = lo * 0x3F80u + hi * 0x3F800000u;
      }
      *(uint4*)aw_dst = aw;
    }
#pragma unroll
    for (int i = 0; i < 4; ++i) {
      int rowbase = wave * 64 + i * 16;
      const unsigned short* g = y1sT + (size_t)(rowbase + (lane >> 2)) * NE + k0 + (lane & 3) * 8;
      async_copy16(g, &b_lds[rowbase * 32]);
    }
    if (wave == 3) {
      const unsigned short* g = y1sT + (size_t)(256 + (lane >> 2)) * NE + k0 + (lane & 3) * 8;
      async_copy16(g, &b_lds[256 * 32]);
    }
    __syncthreads();
    if (kk + 32 < KS) {
      agp += 4;
      abyte = *agp;
    }
    bf16x8 af[4];
#pragma unroll
    for (int i = 0; i < 4; ++i)
      af[i] = *(const bf16x8*)&a_lds[(i * 16 + l15) * 40 + quad * 8];
#pragma unroll
    for (int j = 0; j < 4; ++j) {
      bf16x8 bfr = *(const bf16x8*)&b_lds[(wave * 64 + j * 16 + l15) * 32 + quad * 8];
#pragma unroll
      for (int i = 0; i < 4; ++i)
        acc[i][j] = __builtin_amdgcn_mfma_f32_16x16x32_bf16(af[i], bfr, acc[i][j], 0, 0, 0);
    }
    if (wave == 3) {
      bf16x8 bfr = *(const bf16x8*)&b_lds[(256 + l15) * 32 + quad * 8];
#pragma unroll
      for (int i = 0; i < 4; ++i)
        acc5[i] = __builtin_amdgcn_mfma_f32_16x16x32_bf16(af[i], bfr, acc5[i], 0, 0, 0);
    }
  }
  float* outp = mm2p + (size_t)sp * NN * CH;
#pragma unroll
  for (int i = 0; i < 4; ++i) {
    int row4 = m0 + i * 16 + quad * 4;
#pragma unroll
    for (int j = 0; j < 4; ++j) {
      int col = wave * 64 + j * 16 + l15;
#pragma unroll
      for (int r = 0; r < 4; ++r) outp[(size_t)(row4 + r) * CH + col] = acc[i][j][r];
    }
  }
  if (wave == 3 && l15 == 0) {
#pragma unroll
    for (int i = 0; i < 4; ++i) {
      int row4 = m0 + i * 16 + quad * 4;
#pragma unroll
      for (int r = 0; r < 4; ++r) d0p[(size_t)sp * NN + row4 + r] = acc5[i][r];
    }
  }
}

// ---------------- K6: node finalize (reduce 4 partials) ----------------
__global__ void k6_node_final(const float* __restrict__ mm2p, const float* __restrict__ d0p,
                              const float* __restrict__ b10, float* __restrict__ out0) {
  int n = blockIdx.x, c = threadIdx.x;
  float s = 0.f, d = 0.f;
#pragma unroll
  for (int sp = 0; sp < MM2_SPLIT; ++sp) {
    s += mm2p[(size_t)sp * NN * CH + (size_t)n * CH + c];
    d += d0p[(size_t)sp * NN + n];
  }
  float v = s / d + b10[c];
  out0[(size_t)n * CH + c] = fmaxf(v, 0.f);
}

extern "C" void kernel_launch(void* const* d_in, const int* in_sizes, int n_in,
                              void* d_out, int out_size, void* d_ws, size_t ws_size,
                              hipStream_t stream) {
  const float* x0 = (const float*)d_in[0];
  const float* B1 = (const float*)d_in[1];
  const float* W0 = (const float*)d_in[2];
  const float* W1 = (const float*)d_in[3];
  const float* b01 = (const float*)d_in[4];
  const float* b10 = (const float*)d_in[5];
  float* out0 = (float*)d_out;
  float* out1 = out0 + (size_t)NN * CH;

  char* ws = (char*)d_ws;
  size_t off = 0;
  auto take = [&](size_t bytes) {
    void* p = ws + off;
    off += (bytes + 255) & ~(size_t)255;
    return p;
  };
  unsigned short* y0sT = (unsigned short*)take((size_t)272 * NN * 2);          // 8.9 MB
  unsigned short* y1sT = (unsigned short*)take((size_t)272 * NE * 2);          // 4.5 MB
  unsigned short* x1bf = (unsigned short*)take((size_t)NE * CH * 2);           // 4.2 MB
  float* mm1p = (float*)take((size_t)MM1_SPLIT * NE * CH * 4);                 // 67.1 MB
  float* mm2p = mm1p;  // alias: mm1p dead after K3; MM2_SPLIT*NN*CH*4 == same size
  float* node_card = (float*)take((size_t)NN * 4);
  float* edge_card = (float*)take((size_t)NE * 4);
  float* auxD = (float*)take((size_t)MM1_SPLIT * NE * 4);
  float* auxC = (float*)take((size_t)MM1_SPLIT * NE * 4);
  float* d0p = (float*)take((size_t)MM2_SPLIT * NN * 4);
  unsigned short* W0T = (unsigned short*)take((size_t)CH * CH * 2);
  unsigned short* W1T = (unsigned short*)take((size_t)CH * CH * 2);
  unsigned* pk1 = (unsigned*)take((size_t)NN * 256 * 4);                       // 16.8 MB packed B1
  unsigned* pk1T = (unsigned*)take((size_t)NE * 512 * 4);                      // 16.8 MB packed B1^T
  (void)ws_size; (void)in_sizes; (void)n_in; (void)out_size;

  k0_transpose_w<<<dim3(256, 2), 256, 0, stream>>>(W0, W1, W0T, W1T);
  k1_pack_card<<<NN, 256, 0, stream>>>(B1, pk1, node_card);
  k1b_bitT<<<256, 256, 0, stream>>>(pk1, pk1T);
  k2_y0<<<NN / 64, 256, 0, stream>>>(x0, W0T, node_card, y0sT);
  k2b_aux<<<NN / 256, 256, 0, stream>>>(node_card, y0sT);
  mm1_kernel<<<dim3(NE / 64, MM1_SPLIT), 256, 0, stream>>>((const unsigned char*)pk1T, y0sT, mm1p, auxD, auxC);
  k3_edge_final<<<NE, 256, 0, stream>>>(mm1p, auxD, auxC, b01, out1, x1bf, edge_card);
  k5_y1<<<NE / 64, 256, 0, stream>>>(x1bf, W1T, edge_card, y1sT);
  k5b_aux<<<NE / 256, 256, 0, stream>>>(edge_card, y1sT);
  mm2_kernel<<<dim3(NN / 64, MM2_SPLIT), 256, 0, stream>>>((const unsigned char*)pk1, y1sT, mm2p, d0p);
  k6_node_final<<<NN, 256, 0, stream>>>(mm2p, d0p, b10, out0);
}

// Round 2
// 977.246 us; speedup vs baseline: 1.1763x; 1.1105x over previous
//
// HNHN layer on MI355X (gfx950). Round 4: BM=128 MM tiles + XCD-resident K-splits.
// MM1/MM2: 512 threads / 8 waves (64x64 each), BM=128 halves B-panel traffic;
// block-id decode pins each K-split slice to one XCD so B+A (~3.2 MB) are
// per-XCD-L2 resident. Aux sums (d1/d0) via scalar accumulation against the
// staged aux row (saves 16 VGPR, stays under the 128-VGPR occupancy step).
// edge_card = popcount(pk1T row)^-1.5 (new kcs kernel) -> auxC machinery dropped.
// Pipeline:
//   K0:  W0,W1 -> bf16 transposed (W0T/W1T, [n][k])
//   K1:  pack B1 rows -> pk1[n][256 u32] + node_card = popcnt^-0.5
//   K1b: bit-transpose pk1 -> pk1T[e][512 u32]
//   KCS: edge_card[e] = popcnt(pk1T[e])^-1.5
//   K2:  y0 = x0@W0 (MFMA); epilogue: y0sT[c][n] = bf16(node_card[n]*y0[n,c])
//   K2b: y0sT aux rows: 256=node_card, 257..271 pad
//   MM1: mm1p[sp] = B1^T-slice @ y0s (split=8, sp=XCD; BM=128; daux=d1 partial)
//   K3:  x1 = sum(p)/sum(d1)+b01; out1=relu(x1); x1bf=bf16(x1)
//   K5:  y1 = x1@W1 (MFMA); epilogue y1sT[c][e]=bf16(edge_card[e]*y1)
//   K5b: y1sT aux rows
//   MM2: mm2p[sp] = B1-slice @ y1s (split=4, sp=XCD/2; BM=128; daux=d0 partial)
//   K6:  out0 = relu(sum(mm2p)/sum(d0p) + b10)
#include <hip/hip_runtime.h>
#include <stdint.h>

#define NN 16384
#define NE 8192
#define CH 256
#define MM1_SPLIT 8
#define MM2_SPLIT 4

typedef __attribute__((ext_vector_type(8))) short bf16x8;
typedef __attribute__((ext_vector_type(4))) float f32x4;

__device__ __forceinline__ unsigned short f2bf(float f) {  // RNE fp32->bf16
  unsigned u = __float_as_uint(f);
  u += 0x7FFFu + ((u >> 16) & 1u);
  return (unsigned short)(u >> 16);
}
__device__ __forceinline__ void async_copy16(const void* gptr, void* lptr) {
  __builtin_amdgcn_global_load_lds((const __attribute__((address_space(1))) unsigned int*)gptr,
                                   (__attribute__((address_space(3))) unsigned int*)lptr,
                                   16, 0, 0);
}

// LSB-first 32x32 bit transpose: result x'[k] bit j == input x[j] bit k.
__device__ __forceinline__ void transpose32(unsigned* x) {
  const unsigned masks[5] = {0x0000FFFFu, 0x00FF00FFu, 0x0F0F0F0Fu, 0x33333333u, 0x55555555u};
#pragma unroll
  for (int jj = 0; jj < 5; ++jj) {
    const int j = 16 >> jj;
    const unsigned m = masks[jj];
#pragma unroll
    for (int k = 0; k < 32; ++k) {
      if ((k & j) == 0) {
        unsigned t = ((x[k] >> j) ^ x[k + j]) & m;
        x[k] ^= (t << j);
        x[k + j] ^= t;
      }
    }
  }
}

// ---------------- K0: weight transpose to bf16 ----------------
__global__ void k0_transpose_w(const float* __restrict__ W0, const float* __restrict__ W1,
                               unsigned short* __restrict__ W0T, unsigned short* __restrict__ W1T) {
  const float* W = blockIdx.y ? W1 : W0;
  unsigned short* WT = blockIdx.y ? W1T : W0T;
  int n = blockIdx.x;
  int k = threadIdx.x;
  WT[n * CH + k] = f2bf(W[k * CH + n]);
}

// ---------------- K1: pack B1 row to bits + node_card ----------------
__global__ void k1_pack_card(const float* __restrict__ B1, unsigned* __restrict__ pk1,
                             float* __restrict__ node_card) {
  int n = blockIdx.x;
  int t = threadIdx.x;
  const float4* p = (const float4*)(B1 + (size_t)n * NE + t * 32);
  unsigned w = 0;
#pragma unroll
  for (int jj = 0; jj < 8; ++jj) {
    float4 v = p[jj];
    w |= ((__float_as_uint(v.x) >> 23) & 1u) << (4 * jj);
    w |= ((__float_as_uint(v.y) >> 23) & 1u) << (4 * jj + 1);
    w |= ((__float_as_uint(v.z) >> 23) & 1u) << (4 * jj + 2);
    w |= ((__float_as_uint(v.w) >> 23) & 1u) << (4 * jj + 3);
  }
  pk1[(size_t)n * 256 + t] = w;
  int s = __popc(w);
  __shared__ int red[4];
#pragma unroll
  for (int off = 32; off; off >>= 1) s += __shfl_down(s, off, 64);
  if ((t & 63) == 0) red[t >> 6] = s;
  __syncthreads();
  if (t == 0) {
    float tot = (float)(red[0] + red[1] + red[2] + red[3]);
    node_card[n] = rsqrtf(tot);
  }
}

// ---------------- K1b: bit transpose pk1 -> pk1T ----------------
__global__ __launch_bounds__(256) void k1b_bitT(const unsigned* __restrict__ pk1,
                                                unsigned* __restrict__ pk1T) {
  int bw = blockIdx.x & 127;   // e-word pair: words 2bw, 2bw+1 (e-range 64)
  int half = blockIdx.x >> 7;  // which half of the 512 n-tiles
  int t = threadIdx.x;
  int nt = half * 256 + t;     // n-word tile 0..511
  unsigned x0[32], x1[32];
#pragma unroll
  for (int r = 0; r < 32; ++r) {
    uint2 v = *(const uint2*)&pk1[(size_t)(nt * 32 + r) * 256 + 2 * bw];
    x0[r] = v.x;
    x1[r] = v.y;
  }
  transpose32(x0);
  transpose32(x1);
  int e0 = bw * 64;
#pragma unroll
  for (int c = 0; c < 32; ++c) {
    pk1T[(size_t)(e0 + c) * 512 + nt] = x0[c];
    pk1T[(size_t)(e0 + 32 + c) * 512 + nt] = x1[c];
  }
}

// ---------------- KCS: edge_card from popcount of pk1T rows ----------------
__global__ void kcs_edge_card(const unsigned* __restrict__ pk1T, float* __restrict__ edge_card) {
  int lane = threadIdx.x & 63;
  int e = blockIdx.x * 4 + (threadIdx.x >> 6);
  const uint4* p = (const uint4*)(pk1T + (size_t)e * 512) + lane * 2;
  uint4 a = p[0], b = p[1];
  int s = __popc(a.x) + __popc(a.y) + __popc(a.z) + __popc(a.w) +
          __popc(b.x) + __popc(b.y) + __popc(b.z) + __popc(b.w);
#pragma unroll
  for (int off = 32; off; off >>= 1) s += __shfl_down(s, off, 64);
  if (lane == 0) {
    float cs = (float)s;
    edge_card[e] = 1.0f / (cs * sqrtf(cs));  // cs^-1.5
  }
}

// ---------------- K2: y0 GEMM + scaled transpose epilogue ----------------
__global__ __launch_bounds__(256) void k2_y0(const float* __restrict__ X0,
                                             const unsigned short* __restrict__ W0T,
                                             const float* __restrict__ node_card,
                                             unsigned short* __restrict__ y0sT) {
  __shared__ __align__(16) unsigned short a_lds[64 * 32];
  __shared__ __align__(16) unsigned short b_lds[256 * 32];
  const int tid = threadIdx.x;
  const int wave = tid >> 6, lane = tid & 63;
  const int quad = lane >> 4, l15 = lane & 15;
  const int m0 = blockIdx.x * 64;
  const int ar = tid >> 3, ac = (tid & 7) * 4;

  f32x4 acc[4][4];
  const f32x4 fz = {0.f, 0.f, 0.f, 0.f};
#pragma unroll
  for (int i = 0; i < 4; ++i)
#pragma unroll
    for (int j = 0; j < 4; ++j) acc[i][j] = fz;

  for (int k0 = 0; k0 < CH; k0 += 32) {
    __syncthreads();
#pragma unroll
    for (int p = 0; p < 2; ++p) {
      float4 v = *(const float4*)(X0 + (size_t)(m0 + ar + p * 32) * CH + k0 + ac);
      uint2 w;
      w.x = ((unsigned)f2bf(v.x)) | ((unsigned)f2bf(v.y) << 16);
      w.y = ((unsigned)f2bf(v.z)) | ((unsigned)f2bf(v.w) << 16);
      *(uint2*)&a_lds[(ar + p * 32) * 32 + ac] = w;
    }
#pragma unroll
    for (int i = 0; i < 4; ++i) {
      int rowbase = wave * 64 + i * 16;
      const unsigned short* g = W0T + (size_t)(rowbase + (lane >> 2)) * CH + k0 + (lane & 3) * 8;
      async_copy16(g, &b_lds[rowbase * 32]);
    }
    __syncthreads();
    bf16x8 af[4];
#pragma unroll
    for (int i = 0; i < 4; ++i)
      af[i] = *(const bf16x8*)&a_lds[(i * 16 + l15) * 32 + quad * 8];
#pragma unroll
    for (int j = 0; j < 4; ++j) {
      bf16x8 bfr = *(const bf16x8*)&b_lds[(wave * 64 + j * 16 + l15) * 32 + quad * 8];
#pragma unroll
      for (int i = 0; i < 4; ++i)
        acc[i][j] = __builtin_amdgcn_mfma_f32_16x16x32_bf16(af[i], bfr, acc[i][j], 0, 0, 0);
    }
  }
#pragma unroll
  for (int i = 0; i < 4; ++i) {
    int row4 = m0 + i * 16 + quad * 4;
    float4 nc = *(const float4*)(node_card + row4);
#pragma unroll
    for (int j = 0; j < 4; ++j) {
      int col = wave * 64 + j * 16 + l15;
      f32x4 v = acc[i][j];
      ushort4 o;
      o.x = f2bf(v[0] * nc.x);
      o.y = f2bf(v[1] * nc.y);
      o.z = f2bf(v[2] * nc.z);
      o.w = f2bf(v[3] * nc.w);
      *(ushort4*)&y0sT[(size_t)col * NN + row4] = o;
    }
  }
}

// ---------------- K2b: y0sT aux rows ----------------
__global__ void k2b_aux(const float* __restrict__ node_card, unsigned short* __restrict__ y0sT) {
  int n = blockIdx.x * 256 + threadIdx.x;
  y0sT[(size_t)256 * NN + n] = f2bf(node_card[n]);
#pragma unroll
  for (int r = 257; r < 272; ++r) y0sT[(size_t)r * NN + n] = 0;
}

// ---------------- MM1: B1^T @ y0s (BM=128, split=8, sp pinned to XCD) ------
// 512 threads / 8 waves (wm=wave>>2 selects row-half, wn=wave&3 col-quarter).
// a_lds row stride 40 shorts; byte-expand swizzle mirrors af[] read pattern.
// d1 partial (sum node_card*B1) accumulated scalar against staged aux row.
__global__ __launch_bounds__(512, 4) void mm1_kernel(const unsigned char* __restrict__ pk1T,
                                                     const unsigned short* __restrict__ y0sT,
                                                     float* __restrict__ mm1p,
                                                     float* __restrict__ auxD) {
  __shared__ __align__(16) unsigned short a_lds[128 * 40];
  __shared__ __align__(16) unsigned short b_lds[272 * 32];
  const int tid = threadIdx.x;
  const int wave = tid >> 6, lane = tid & 63;
  const int quad = lane >> 4, l15 = lane & 15;
  const int wm = wave >> 2, wn = wave & 3;
  const int bid = blockIdx.x;
  const int sp = bid & 7;            // XCD-pinned K-split (dispatch round-robins id%8)
  const int m0 = (bid >> 3) * 128;   // e-range
  const int KS = NN / MM1_SPLIT;     // 2048
  const int kbase = sp * KS;

  const int am = tid >> 2;                 // e-row within tile (0..127)
  const int akg = tid & 3;                 // logical k-group (8 bf16 = 1 byte)
  const int ajbs = akg ^ ((am >> 4) & 3);  // swizzled physical group
  unsigned short* aw_dst = &a_lds[am * 40 + ajbs * 8];

  f32x4 acc[4][4];
  const f32x4 fz = {0.f, 0.f, 0.f, 0.f};
#pragma unroll
  for (int i = 0; i < 4; ++i)
#pragma unroll
    for (int j = 0; j < 4; ++j) acc[i][j] = fz;
  float daux = 0.f;

  const unsigned char* agp = pk1T + (size_t)(m0 + am) * (NN / 8) + (kbase >> 3) + akg;
  unsigned abyte = *agp;  // prefetched A byte

  for (int kk = 0; kk < KS; kk += 32) {
    const int k0 = kbase + kk;
    const unsigned abcur = abyte;
    __syncthreads();
    {  // expand 8 bits -> 8 bf16 {0,1} along k, single b128 LDS write
      uint4 aw;
#pragma unroll
      for (int j = 0; j < 4; ++j) {
        unsigned lo = (abcur >> (2 * j)) & 1u;
        unsigned hi = (abcur >> (2 * j + 1)) & 1u;
        ((unsigned*)&aw)[j] = lo * 0x3F80u + hi * 0x3F800000u;
      }
      *(uint4*)aw_dst = aw;
    }
    // B stage: 8 waves x 32 rows + aux row block by wave 7
#pragma unroll
    for (int i = 0; i < 2; ++i) {
      int rowbase = wave * 32 + i * 16;
      const unsigned short* g = y0sT + (size_t)(rowbase + (lane >> 2)) * NN + k0 + (lane & 3) * 8;
      async_copy16(g, &b_lds[rowbase * 32]);
    }
    if (wave == 7) {
      const unsigned short* g = y0sT + (size_t)(256 + (lane >> 2)) * NN + k0 + (lane & 3) * 8;
      async_copy16(g, &b_lds[256 * 32]);
    }
    __syncthreads();
    // Prefetch next iteration's A byte (overlaps MFMA phase)
    if (kk + 32 < KS) {
      agp += 4;
      abyte = *agp;
    }
    // d1 partial: this thread's 8 k-bits vs node_card (aux row 256)
    {
      bf16x8 nc8 = *(const bf16x8*)&b_lds[256 * 32 + akg * 8];
      float part = 0.f;
#pragma unroll
      for (int j = 0; j < 8; ++j) {
        float ncf = __uint_as_float(((unsigned)(unsigned short)nc8[j]) << 16);
        part += ((abcur >> j) & 1u) ? ncf : 0.f;
      }
      daux += part;
    }
    bf16x8 af[4];
#pragma unroll
    for (int i = 0; i < 4; ++i) {
      int m = wm * 64 + i * 16 + l15;
      int jbs = quad ^ i;  // == quad ^ ((m>>4)&3)
      af[i] = *(const bf16x8*)&a_lds[m * 40 + jbs * 8];
    }
#pragma unroll
    for (int j = 0; j < 4; ++j) {
      bf16x8 bfr = *(const bf16x8*)&b_lds[(wn * 64 + j * 16 + l15) * 32 + quad * 8];
#pragma unroll
      for (int i = 0; i < 4; ++i)
        acc[i][j] = __builtin_amdgcn_mfma_f32_16x16x32_bf16(af[i], bfr, acc[i][j], 0, 0, 0);
    }
  }
  float* outp = mm1p + (size_t)sp * NE * CH;
#pragma unroll
  for (int i = 0; i < 4; ++i) {
    int row4 = m0 + wm * 64 + i * 16 + quad * 4;
#pragma unroll
    for (int j = 0; j < 4; ++j) {
      int col = wn * 64 + j * 16 + l15;
#pragma unroll
      for (int r = 0; r < 4; ++r) outp[(size_t)(row4 + r) * CH + col] = acc[i][j][r];
    }
  }
  // reduce daux over the 4 k-group threads of each row (reuse a_lds)
  __syncthreads();
  float* dred = (float*)a_lds;
  dred[tid] = daux;
  __syncthreads();
  if (tid < 128) {
    float s = dred[tid * 4] + dred[tid * 4 + 1] + dred[tid * 4 + 2] + dred[tid * 4 + 3];
    auxD[(size_t)sp * NE + m0 + tid] = s;
  }
}

// ---------------- K3: edge finalize (reduce 8 partials) ----------------
__global__ void k3_edge_final(const float* __restrict__ mm1p, const float* __restrict__ auxD,
                              const float* __restrict__ b01,
                              float* __restrict__ out1, unsigned short* __restrict__ x1bf) {
  int e = blockIdx.x, c = threadIdx.x;
  float ds = 0.f, p = 0.f;
#pragma unroll
  for (int sp = 0; sp < MM1_SPLIT; ++sp) {
    ds += auxD[(size_t)sp * NE + e];
    p += mm1p[(size_t)sp * NE * CH + (size_t)e * CH + c];
  }
  float x1 = p / ds + b01[c];
  out1[(size_t)e * CH + c] = fmaxf(x1, 0.f);
  x1bf[(size_t)e * CH + c] = f2bf(x1);
}

// ---------------- K5: y1 GEMM + scaled transpose epilogue ----------------
__global__ __launch_bounds__(256) void k5_y1(const unsigned short* __restrict__ x1bf,
                                             const unsigned short* __restrict__ W1T,
                                             const float* __restrict__ edge_card,
                                             unsigned short* __restrict__ y1sT) {
  __shared__ __align__(16) unsigned short a_lds[64 * 32];
  __shared__ __align__(16) unsigned short b_lds[256 * 32];
  const int tid = threadIdx.x;
  const int wave = tid >> 6, lane = tid & 63;
  const int quad = lane >> 4, l15 = lane & 15;
  const int m0 = blockIdx.x * 64;  // e-range

  f32x4 acc[4][4];
  const f32x4 fz = {0.f, 0.f, 0.f, 0.f};
#pragma unroll
  for (int i = 0; i < 4; ++i)
#pragma unroll
    for (int j = 0; j < 4; ++j) acc[i][j] = fz;

  for (int k0 = 0; k0 < CH; k0 += 32) {
    __syncthreads();
    {  // A: bf16 already, async copy. 16 rows per wave.
      const unsigned short* g = x1bf + (size_t)(m0 + wave * 16 + (lane >> 2)) * CH + k0 + (lane & 3) * 8;
      async_copy16(g, &a_lds[(wave * 16) * 32]);
    }
#pragma unroll
    for (int i = 0; i < 4; ++i) {
      int rowbase = wave * 64 + i * 16;
      const unsigned short* g = W1T + (size_t)(rowbase + (lane >> 2)) * CH + k0 + (lane & 3) * 8;
      async_copy16(g, &b_lds[rowbase * 32]);
    }
    __syncthreads();
    bf16x8 af[4];
#pragma unroll
    for (int i = 0; i < 4; ++i)
      af[i] = *(const bf16x8*)&a_lds[(i * 16 + l15) * 32 + quad * 8];
#pragma unroll
    for (int j = 0; j < 4; ++j) {
      bf16x8 bfr = *(const bf16x8*)&b_lds[(wave * 64 + j * 16 + l15) * 32 + quad * 8];
#pragma unroll
      for (int i = 0; i < 4; ++i)
        acc[i][j] = __builtin_amdgcn_mfma_f32_16x16x32_bf16(af[i], bfr, acc[i][j], 0, 0, 0);
    }
  }
#pragma unroll
  for (int i = 0; i < 4; ++i) {
    int row4 = m0 + i * 16 + quad * 4;
    float4 ec = *(const float4*)(edge_card + row4);
#pragma unroll
    for (int j = 0; j < 4; ++j) {
      int col = wave * 64 + j * 16 + l15;
      f32x4 v = acc[i][j];
      ushort4 o;
      o.x = f2bf(v[0] * ec.x);
      o.y = f2bf(v[1] * ec.y);
      o.z = f2bf(v[2] * ec.z);
      o.w = f2bf(v[3] * ec.w);
      *(ushort4*)&y1sT[(size_t)col * NE + row4] = o;
    }
  }
}

// ---------------- K5b: y1sT aux rows ----------------
__global__ void k5b_aux(const float* __restrict__ edge_card, unsigned short* __restrict__ y1sT) {
  int e = blockIdx.x * 256 + threadIdx.x;
  y1sT[(size_t)256 * NE + e] = f2bf(edge_card[e]);
#pragma unroll
  for (int r = 257; r < 272; ++r) y1sT[(size_t)r * NE + e] = 0;
}

// ---------------- MM2: B1 @ y1s (BM=128, split=4, sp pinned to XCD pair) ----
__global__ __launch_bounds__(512, 4) void mm2_kernel(const unsigned char* __restrict__ pk1,
                                                     const unsigned short* __restrict__ y1sT,
                                                     float* __restrict__ mm2p,
                                                     float* __restrict__ d0p) {
  __shared__ __align__(16) unsigned short a_lds[128 * 40];
  __shared__ __align__(16) unsigned short b_lds[272 * 32];
  const int tid = threadIdx.x;
  const int wave = tid >> 6, lane = tid & 63;
  const int quad = lane >> 4, l15 = lane & 15;
  const int wm = wave >> 2, wn = wave & 3;
  const int bid = blockIdx.x;
  const int sp = (bid >> 1) & 3;                    // XCD pair {2sp,2sp+1}
  const int m0 = (((bid >> 3) << 1) | (bid & 1)) * 128;  // node-range
  const int KS = NE / MM2_SPLIT;                    // 2048
  const int kbase = sp * KS;

  const int am = tid >> 2;
  const int akg = tid & 3;
  const int ajbs = akg ^ ((am >> 4) & 3);
  unsigned short* aw_dst = &a_lds[am * 40 + ajbs * 8];

  f32x4 acc[4][4];
  const f32x4 fz = {0.f, 0.f, 0.f, 0.f};
#pragma unroll
  for (int i = 0; i < 4; ++i)
#pragma unroll
    for (int j = 0; j < 4; ++j) acc[i][j] = fz;
  float daux = 0.f;

  const unsigned char* agp = pk1 + (size_t)(m0 + am) * (NE / 8) + (kbase >> 3) + akg;
  unsigned abyte = *agp;

  for (int kk = 0; kk < KS; kk += 32) {
    const int k0 = kbase + kk;
    const unsigned abcur = abyte;
    __syncthreads();
    {
      uint4 aw;
#pragma unroll
      for (int j = 0; j < 4; ++j) {
        unsigned lo = (abcur >> (2 * j)) & 1u;
        unsigned hi = (abcur >> (2 * j + 1)) & 1u;
        ((unsigned*)&aw)[j] = lo * 0x3F80u + hi * 0x3F800000u;
      }
      *(uint4*)aw_dst = aw;
    }
#pragma unroll
    for (int i = 0; i < 2; ++i) {
      int rowbase = wave * 32 + i * 16;
      const unsigned short* g = y1sT + (size_t)(rowbase + (lane >> 2)) * NE + k0 + (lane & 3) * 8;
      async_copy16(g, &b_lds[rowbase * 32]);
    }
    if (wave == 7) {
      const unsigned short* g = y1sT + (size_t)(256 + (lane >> 2)) * NE + k0 + (lane & 3) * 8;
      async_copy16(g, &b_lds[256 * 32]);
    }
    __syncthreads();
    if (kk + 32 < KS) {
      agp += 4;
      abyte = *agp;
    }
    {  // d0 partial: bits vs edge_card (aux row 256)
      bf16x8 ec8 = *(const bf16x8*)&b_lds[256 * 32 + akg * 8];
      float part = 0.f;
#pragma unroll
      for (int j = 0; j < 8; ++j) {
        float ecf = __uint_as_float(((unsigned)(unsigned short)ec8[j]) << 16);
        part += ((abcur >> j) & 1u) ? ecf : 0.f;
      }
      daux += part;
    }
    bf16x8 af[4];
#pragma unroll
    for (int i = 0; i < 4; ++i) {
      int m = wm * 64 + i * 16 + l15;
      int jbs = quad ^ i;
      af[i] = *(const bf16x8*)&a_lds[m * 40 + jbs * 8];
    }
#pragma unroll
    for (int j = 0; j < 4; ++j) {
      bf16x8 bfr = *(const bf16x8*)&b_lds[(wn * 64 + j * 16 + l15) * 32 + quad * 8];
#pragma unroll
      for (int i = 0; i < 4; ++i)
        acc[i][j] = __builtin_amdgcn_mfma_f32_16x16x32_bf16(af[i], bfr, acc[i][j], 0, 0, 0);
    }
  }
  float* outp = mm2p + (size_t)sp * NN * CH;
#pragma unroll
  for (int i = 0; i < 4; ++i) {
    int row4 = m0 + wm * 64 + i * 16 + quad * 4;
#pragma unroll
    for (int j = 0; j < 4; ++j) {
      int col = wn * 64 + j * 16 + l15;
#pragma unroll
      for (int r = 0; r < 4; ++r) outp[(size_t)(row4 + r) * CH + col] = acc[i][j][r];
    }
  }
  __syncthreads();
  float* dred = (float*)a_lds;
  dred[tid] = daux;
  __syncthreads();
  if (tid < 128) {
    float s = dred[tid * 4] + dred[tid * 4 + 1] + dred[tid * 4 + 2] + dred[tid * 4 + 3];
    d0p[(size_t)sp * NN + m0 + tid] = s;
  }
}

// ---------------- K6: node finalize (reduce 4 partials) ----------------
__global__ void k6_node_final(const float* __restrict__ mm2p, const float* __restrict__ d0p,
                              const float* __restrict__ b10, float* __restrict__ out0) {
  int n = blockIdx.x, c = threadIdx.x;
  float s = 0.f, d = 0.f;
#pragma unroll
  for (int sp = 0; sp < MM2_SPLIT; ++sp) {
    s += mm2p[(size_t)sp * NN * CH + (size_t)n * CH + c];
    d += d0p[(size_t)sp * NN + n];
  }
  float v = s / d + b10[c];
  out0[(size_t)n * CH + c] = fmaxf(v, 0.f);
}

extern "C" void kernel_launch(void* const* d_in, const int* in_sizes, int n_in,
                              void* d_out, int out_size, void* d_ws, size_t ws_size,
                              hipStream_t stream) {
  const float* x0 = (const float*)d_in[0];
  const float* B1 = (const float*)d_in[1];
  const float* W0 = (const float*)d_in[2];
  const float* W1 = (const float*)d_in[3];
  const float* b01 = (const float*)d_in[4];
  const float* b10 = (const float*)d_in[5];
  float* out0 = (float*)d_out;
  float* out1 = out0 + (size_t)NN * CH;

  char* ws = (char*)d_ws;
  size_t off = 0;
  auto take = [&](size_t bytes) {
    void* p = ws + off;
    off += (bytes + 255) & ~(size_t)255;
    return p;
  };
  unsigned short* y0sT = (unsigned short*)take((size_t)272 * NN * 2);          // 8.9 MB
  unsigned short* y1sT = (unsigned short*)take((size_t)272 * NE * 2);          // 4.5 MB
  unsigned short* x1bf = (unsigned short*)take((size_t)NE * CH * 2);           // 4.2 MB
  float* mm1p = (float*)take((size_t)MM1_SPLIT * NE * CH * 4);                 // 67.1 MB
  float* mm2p = mm1p;  // alias: mm1p dead after K3; MM2_SPLIT*NN*CH*4 == same size
  float* node_card = (float*)take((size_t)NN * 4);
  float* edge_card = (float*)take((size_t)NE * 4);
  float* auxD = (float*)take((size_t)MM1_SPLIT * NE * 4);
  float* d0p = (float*)take((size_t)MM2_SPLIT * NN * 4);
  unsigned short* W0T = (unsigned short*)take((size_t)CH * CH * 2);
  unsigned short* W1T = (unsigned short*)take((size_t)CH * CH * 2);
  unsigned* pk1 = (unsigned*)take((size_t)NN * 256 * 4);                       // 16.8 MB packed B1
  unsigned* pk1T = (unsigned*)take((size_t)NE * 512 * 4);                      // 16.8 MB packed B1^T
  (void)ws_size; (void)in_sizes; (void)n_in; (void)out_size;

  k0_transpose_w<<<dim3(256, 2), 256, 0, stream>>>(W0, W1, W0T, W1T);
  k1_pack_card<<<NN, 256, 0, stream>>>(B1, pk1, node_card);
  k1b_bitT<<<256, 256, 0, stream>>>(pk1, pk1T);
  kcs_edge_card<<<NE / 4, 256, 0, stream>>>(pk1T, edge_card);
  k2_y0<<<NN / 64, 256, 0, stream>>>(x0, W0T, node_card, y0sT);
  k2b_aux<<<NN / 256, 256, 0, stream>>>(node_card, y0sT);
  mm1_kernel<<<512, 512, 0, stream>>>((const unsigned char*)pk1T, y0sT, mm1p, auxD);
  k3_edge_final<<<NE, 256, 0, stream>>>(mm1p, auxD, b01, out1, x1bf);
  k5_y1<<<NE / 64, 256, 0, stream>>>(x1bf, W1T, edge_card, y1sT);
  k5b_aux<<<NE / 256, 256, 0, stream>>>(edge_card, y1sT);
  mm2_kernel<<<512, 512, 0, stream>>>((const unsigned char*)pk1, y1sT, mm2p, d0p);
  k6_node_final<<<NN, 256, 0, stream>>>(mm2p, d0p, b10, out0);
}

// Round 3
// 973.986 us; speedup vs baseline: 1.1802x; 1.0033x over previous
//
// HNHN layer on MI355X (gfx950). Round 5: double-buffered MM K-loops.
// MM1/MM2 now single-barrier-per-iteration: stage tile t+1 (async B copies +
// A byte-expand ds_write) into buffer ^1 BEFORE computing tile t, so the
// __syncthreads() vmcnt drain lands after the MFMA window (T3 minimum-2-phase).
// Keeps R4's BM=128 / 8-wave blocks / XCD-pinned K-splits / bit-packed A.
// Pipeline:
//   K0:  W0,W1 -> bf16 transposed (W0T/W1T, [n][k])
//   K1:  pack B1 rows -> pk1[n][256 u32] + node_card = popcnt^-0.5
//   K1b: bit-transpose pk1 -> pk1T[e][512 u32]
//   KCS: edge_card[e] = popcnt(pk1T[e])^-1.5
//   K2:  y0 = x0@W0 (MFMA); epilogue: y0sT[c][n] = bf16(node_card[n]*y0[n,c])
//   K2b: y0sT aux row 256 = node_card
//   MM1: mm1p[sp] = B1^T-slice @ y0s (split=8, sp=XCD; BM=128; dbuf; daux=d1)
//   K3:  x1 = sum(p)/sum(d1)+b01; out1=relu(x1); x1bf=bf16(x1)
//   K5:  y1 = x1@W1 (MFMA); epilogue y1sT[c][e]=bf16(edge_card[e]*y1)
//   K5b: y1sT aux row 256 = edge_card
//   MM2: mm2p[sp] = B1-slice @ y1s (split=4, sp=XCD pair; BM=128; dbuf; daux=d0)
//   K6:  out0 = relu(sum(mm2p)/sum(d0p) + b10)
#include <hip/hip_runtime.h>
#include <stdint.h>

#define NN 16384
#define NE 8192
#define CH 256
#define MM1_SPLIT 8
#define MM2_SPLIT 4

typedef __attribute__((ext_vector_type(8))) short bf16x8;
typedef __attribute__((ext_vector_type(4))) float f32x4;

__device__ __forceinline__ unsigned short f2bf(float f) {  // RNE fp32->bf16
  unsigned u = __float_as_uint(f);
  u += 0x7FFFu + ((u >> 16) & 1u);
  return (unsigned short)(u >> 16);
}
__device__ __forceinline__ void async_copy16(const void* gptr, void* lptr) {
  __builtin_amdgcn_global_load_lds((const __attribute__((address_space(1))) unsigned int*)gptr,
                                   (__attribute__((address_space(3))) unsigned int*)lptr,
                                   16, 0, 0);
}
// expand 8 A-bits -> 8 bf16 {0,1} packed in uint4 (2 bf16 per u32)
__device__ __forceinline__ uint4 expand8(unsigned byte) {
  uint4 aw;
#pragma unroll
  for (int j = 0; j < 4; ++j) {
    unsigned lo = (byte >> (2 * j)) & 1u;
    unsigned hi = (byte >> (2 * j + 1)) & 1u;
    ((unsigned*)&aw)[j] = lo * 0x3F80u + hi * 0x3F800000u;
  }
  return aw;
}

// LSB-first 32x32 bit transpose: result x'[k] bit j == input x[j] bit k.
__device__ __forceinline__ void transpose32(unsigned* x) {
  const unsigned masks[5] = {0x0000FFFFu, 0x00FF00FFu, 0x0F0F0F0Fu, 0x33333333u, 0x55555555u};
#pragma unroll
  for (int jj = 0; jj < 5; ++jj) {
    const int j = 16 >> jj;
    const unsigned m = masks[jj];
#pragma unroll
    for (int k = 0; k < 32; ++k) {
      if ((k & j) == 0) {
        unsigned t = ((x[k] >> j) ^ x[k + j]) & m;
        x[k] ^= (t << j);
        x[k + j] ^= t;
      }
    }
  }
}

// ---------------- K0: weight transpose to bf16 ----------------
__global__ void k0_transpose_w(const float* __restrict__ W0, const float* __restrict__ W1,
                               unsigned short* __restrict__ W0T, unsigned short* __restrict__ W1T) {
  const float* W = blockIdx.y ? W1 : W0;
  unsigned short* WT = blockIdx.y ? W1T : W0T;
  int n = blockIdx.x;
  int k = threadIdx.x;
  WT[n * CH + k] = f2bf(W[k * CH + n]);
}

// ---------------- K1: pack B1 row to bits + node_card ----------------
__global__ void k1_pack_card(const float* __restrict__ B1, unsigned* __restrict__ pk1,
                             float* __restrict__ node_card) {
  int n = blockIdx.x;
  int t = threadIdx.x;
  const float4* p = (const float4*)(B1 + (size_t)n * NE + t * 32);
  unsigned w = 0;
#pragma unroll
  for (int jj = 0; jj < 8; ++jj) {
    float4 v = p[jj];
    w |= ((__float_as_uint(v.x) >> 23) & 1u) << (4 * jj);
    w |= ((__float_as_uint(v.y) >> 23) & 1u) << (4 * jj + 1);
    w |= ((__float_as_uint(v.z) >> 23) & 1u) << (4 * jj + 2);
    w |= ((__float_as_uint(v.w) >> 23) & 1u) << (4 * jj + 3);
  }
  pk1[(size_t)n * 256 + t] = w;
  int s = __popc(w);
  __shared__ int red[4];
#pragma unroll
  for (int off = 32; off; off >>= 1) s += __shfl_down(s, off, 64);
  if ((t & 63) == 0) red[t >> 6] = s;
  __syncthreads();
  if (t == 0) {
    float tot = (float)(red[0] + red[1] + red[2] + red[3]);
    node_card[n] = rsqrtf(tot);
  }
}

// ---------------- K1b: bit transpose pk1 -> pk1T ----------------
__global__ __launch_bounds__(256) void k1b_bitT(const unsigned* __restrict__ pk1,
                                                unsigned* __restrict__ pk1T) {
  int bw = blockIdx.x & 127;   // e-word pair: words 2bw, 2bw+1 (e-range 64)
  int half = blockIdx.x >> 7;  // which half of the 512 n-tiles
  int t = threadIdx.x;
  int nt = half * 256 + t;     // n-word tile 0..511
  unsigned x0[32], x1[32];
#pragma unroll
  for (int r = 0; r < 32; ++r) {
    uint2 v = *(const uint2*)&pk1[(size_t)(nt * 32 + r) * 256 + 2 * bw];
    x0[r] = v.x;
    x1[r] = v.y;
  }
  transpose32(x0);
  transpose32(x1);
  int e0 = bw * 64;
#pragma unroll
  for (int c = 0; c < 32; ++c) {
    pk1T[(size_t)(e0 + c) * 512 + nt] = x0[c];
    pk1T[(size_t)(e0 + 32 + c) * 512 + nt] = x1[c];
  }
}

// ---------------- KCS: edge_card from popcount of pk1T rows ----------------
__global__ void kcs_edge_card(const unsigned* __restrict__ pk1T, float* __restrict__ edge_card) {
  int lane = threadIdx.x & 63;
  int e = blockIdx.x * 4 + (threadIdx.x >> 6);
  const uint4* p = (const uint4*)(pk1T + (size_t)e * 512) + lane * 2;
  uint4 a = p[0], b = p[1];
  int s = __popc(a.x) + __popc(a.y) + __popc(a.z) + __popc(a.w) +
          __popc(b.x) + __popc(b.y) + __popc(b.z) + __popc(b.w);
#pragma unroll
  for (int off = 32; off; off >>= 1) s += __shfl_down(s, off, 64);
  if (lane == 0) {
    float cs = (float)s;
    edge_card[e] = 1.0f / (cs * sqrtf(cs));  // cs^-1.5
  }
}

// ---------------- K2: y0 GEMM + scaled transpose epilogue ----------------
__global__ __launch_bounds__(256) void k2_y0(const float* __restrict__ X0,
                                             const unsigned short* __restrict__ W0T,
                                             const float* __restrict__ node_card,
                                             unsigned short* __restrict__ y0sT) {
  __shared__ __align__(16) unsigned short a_lds[64 * 32];
  __shared__ __align__(16) unsigned short b_lds[256 * 32];
  const int tid = threadIdx.x;
  const int wave = tid >> 6, lane = tid & 63;
  const int quad = lane >> 4, l15 = lane & 15;
  const int m0 = blockIdx.x * 64;
  const int ar = tid >> 3, ac = (tid & 7) * 4;

  f32x4 acc[4][4];
  const f32x4 fz = {0.f, 0.f, 0.f, 0.f};
#pragma unroll
  for (int i = 0; i < 4; ++i)
#pragma unroll
    for (int j = 0; j < 4; ++j) acc[i][j] = fz;

  for (int k0 = 0; k0 < CH; k0 += 32) {
    __syncthreads();
#pragma unroll
    for (int p = 0; p < 2; ++p) {
      float4 v = *(const float4*)(X0 + (size_t)(m0 + ar + p * 32) * CH + k0 + ac);
      uint2 w;
      w.x = ((unsigned)f2bf(v.x)) | ((unsigned)f2bf(v.y) << 16);
      w.y = ((unsigned)f2bf(v.z)) | ((unsigned)f2bf(v.w) << 16);
      *(uint2*)&a_lds[(ar + p * 32) * 32 + ac] = w;
    }
#pragma unroll
    for (int i = 0; i < 4; ++i) {
      int rowbase = wave * 64 + i * 16;
      const unsigned short* g = W0T + (size_t)(rowbase + (lane >> 2)) * CH + k0 + (lane & 3) * 8;
      async_copy16(g, &b_lds[rowbase * 32]);
    }
    __syncthreads();
    bf16x8 af[4];
#pragma unroll
    for (int i = 0; i < 4; ++i)
      af[i] = *(const bf16x8*)&a_lds[(i * 16 + l15) * 32 + quad * 8];
#pragma unroll
    for (int j = 0; j < 4; ++j) {
      bf16x8 bfr = *(const bf16x8*)&b_lds[(wave * 64 + j * 16 + l15) * 32 + quad * 8];
#pragma unroll
      for (int i = 0; i < 4; ++i)
        acc[i][j] = __builtin_amdgcn_mfma_f32_16x16x32_bf16(af[i], bfr, acc[i][j], 0, 0, 0);
    }
  }
#pragma unroll
  for (int i = 0; i < 4; ++i) {
    int row4 = m0 + i * 16 + quad * 4;
    float4 nc = *(const float4*)(node_card + row4);
#pragma unroll
    for (int j = 0; j < 4; ++j) {
      int col = wave * 64 + j * 16 + l15;
      f32x4 v = acc[i][j];
      ushort4 o;
      o.x = f2bf(v[0] * nc.x);
      o.y = f2bf(v[1] * nc.y);
      o.z = f2bf(v[2] * nc.z);
      o.w = f2bf(v[3] * nc.w);
      *(ushort4*)&y0sT[(size_t)col * NN + row4] = o;
    }
  }
}

// ---------------- K2b: y0sT aux row (256 = node_card) ----------------
__global__ void k2b_aux(const float* __restrict__ node_card, unsigned short* __restrict__ y0sT) {
  int n = blockIdx.x * 256 + threadIdx.x;
  y0sT[(size_t)256 * NN + n] = f2bf(node_card[n]);
}

// ---------------- MM1: B1^T @ y0s (BM=128, split=8, XCD-pinned, dbuf) ------
__global__ __launch_bounds__(512, 4) void mm1_kernel(const unsigned char* __restrict__ pk1T,
                                                     const unsigned short* __restrict__ y0sT,
                                                     float* __restrict__ mm1p,
                                                     float* __restrict__ auxD) {
  __shared__ __align__(16) unsigned short a_lds[2][128 * 40];
  __shared__ __align__(16) unsigned short b_lds[2][272 * 32];
  const int tid = threadIdx.x;
  const int wave = tid >> 6, lane = tid & 63;
  const int quad = lane >> 4, l15 = lane & 15;
  const int wm = wave >> 2, wn = wave & 3;
  const int bid = blockIdx.x;
  const int sp = bid & 7;            // XCD-pinned K-split
  const int m0 = (bid >> 3) * 128;   // e-range
  const int KS = NN / MM1_SPLIT;     // 2048
  const int NT = KS / 32;            // 64
  const int kbase = sp * KS;

  const int am = tid >> 2;                 // e-row within tile (0..127)
  const int akg = tid & 3;                 // logical k-group (8 bf16 = 1 byte)
  const int ajbs = akg ^ ((am >> 4) & 3);  // swizzled physical group
  const int aoff = am * 40 + ajbs * 8;

  // B-stage source lane offsets
  const int brow = lane >> 2;
  const int bcol = (lane & 3) * 8;

  f32x4 acc[4][4];
  const f32x4 fz = {0.f, 0.f, 0.f, 0.f};
#pragma unroll
  for (int i = 0; i < 4; ++i)
#pragma unroll
    for (int j = 0; j < 4; ++j) acc[i][j] = fz;
  float daux = 0.f;

  const unsigned char* agp = pk1T + (size_t)(m0 + am) * (NN / 8) + (kbase >> 3) + akg;
  unsigned ab_cur = agp[0];  // byte for tile 0
  unsigned ab_nxt = agp[4];  // byte for tile 1
  const unsigned char* agq = agp + 8;

  // prologue: stage tile 0 into buffer 0
#pragma unroll
  for (int i = 0; i < 2; ++i) {
    int rowbase = wave * 32 + i * 16;
    const unsigned short* g = y0sT + (size_t)(rowbase + brow) * NN + kbase + bcol;
    async_copy16(g, &b_lds[0][rowbase * 32]);
  }
  if (wave == 7) {
    const unsigned short* g = y0sT + (size_t)(256 + brow) * NN + kbase + bcol;
    async_copy16(g, &b_lds[0][256 * 32]);
  }
  *(uint4*)&a_lds[0][aoff] = expand8(ab_cur);
  __syncthreads();

  for (int t = 0; t < NT; ++t) {
    const int cur = t & 1;
    unsigned ab_new = 0;
    if (t + 1 < NT) {  // stage tile t+1 into buffer cur^1 (uniform branch)
      const int k0n = kbase + (t + 1) * 32;
#pragma unroll
      for (int i = 0; i < 2; ++i) {
        int rowbase = wave * 32 + i * 16;
        const unsigned short* g = y0sT + (size_t)(rowbase + brow) * NN + k0n + bcol;
        async_copy16(g, &b_lds[cur ^ 1][rowbase * 32]);
      }
      if (wave == 7) {
        const unsigned short* g = y0sT + (size_t)(256 + brow) * NN + k0n + bcol;
        async_copy16(g, &b_lds[cur ^ 1][256 * 32]);
      }
      *(uint4*)&a_lds[cur ^ 1][aoff] = expand8(ab_nxt);
      if (t + 2 < NT) {
        ab_new = *agq;
        agq += 4;
      }
    }
    // d1 partial: this thread's 8 k-bits vs node_card (aux row 256)
    {
      bf16x8 nc8 = *(const bf16x8*)&b_lds[cur][256 * 32 + akg * 8];
      float part = 0.f;
#pragma unroll
      for (int j = 0; j < 8; ++j) {
        float ncf = __uint_as_float(((unsigned)(unsigned short)nc8[j]) << 16);
        part += ((ab_cur >> j) & 1u) ? ncf : 0.f;
      }
      daux += part;
    }
    bf16x8 af[4];
#pragma unroll
    for (int i = 0; i < 4; ++i) {
      int m = wm * 64 + i * 16 + l15;
      int jbs = quad ^ i;  // == quad ^ ((m>>4)&3)
      af[i] = *(const bf16x8*)&a_lds[cur][m * 40 + jbs * 8];
    }
#pragma unroll
    for (int j = 0; j < 4; ++j) {
      bf16x8 bfr = *(const bf16x8*)&b_lds[cur][(wn * 64 + j * 16 + l15) * 32 + quad * 8];
#pragma unroll
      for (int i = 0; i < 4; ++i)
        acc[i][j] = __builtin_amdgcn_mfma_f32_16x16x32_bf16(af[i], bfr, acc[i][j], 0, 0, 0);
    }
    __syncthreads();  // drains vmcnt (tile t+1 B copies) + lgkm; nxt ready
    ab_cur = ab_nxt;
    ab_nxt = ab_new;
  }
  float* outp = mm1p + (size_t)sp * NE * CH;
#pragma unroll
  for (int i = 0; i < 4; ++i) {
    int row4 = m0 + wm * 64 + i * 16 + quad * 4;
#pragma unroll
    for (int j = 0; j < 4; ++j) {
      int col = wn * 64 + j * 16 + l15;
#pragma unroll
      for (int r = 0; r < 4; ++r) outp[(size_t)(row4 + r) * CH + col] = acc[i][j][r];
    }
  }
  // reduce daux over the 4 k-group threads of each row (reuse a_lds[0])
  __syncthreads();
  float* dred = (float*)a_lds;
  dred[tid] = daux;
  __syncthreads();
  if (tid < 128) {
    float s = dred[tid * 4] + dred[tid * 4 + 1] + dred[tid * 4 + 2] + dred[tid * 4 + 3];
    auxD[(size_t)sp * NE + m0 + tid] = s;
  }
}

// ---------------- K3: edge finalize (reduce 8 partials) ----------------
__global__ void k3_edge_final(const float* __restrict__ mm1p, const float* __restrict__ auxD,
                              const float* __restrict__ b01,
                              float* __restrict__ out1, unsigned short* __restrict__ x1bf) {
  int e = blockIdx.x, c = threadIdx.x;
  float ds = 0.f, p = 0.f;
#pragma unroll
  for (int sp = 0; sp < MM1_SPLIT; ++sp) {
    ds += auxD[(size_t)sp * NE + e];
    p += mm1p[(size_t)sp * NE * CH + (size_t)e * CH + c];
  }
  float x1 = p / ds + b01[c];
  out1[(size_t)e * CH + c] = fmaxf(x1, 0.f);
  x1bf[(size_t)e * CH + c] = f2bf(x1);
}

// ---------------- K5: y1 GEMM + scaled transpose epilogue ----------------
__global__ __launch_bounds__(256) void k5_y1(const unsigned short* __restrict__ x1bf,
                                             const unsigned short* __restrict__ W1T,
                                             const float* __restrict__ edge_card,
                                             unsigned short* __restrict__ y1sT) {
  __shared__ __align__(16) unsigned short a_lds[64 * 32];
  __shared__ __align__(16) unsigned short b_lds[256 * 32];
  const int tid = threadIdx.x;
  const int wave = tid >> 6, lane = tid & 63;
  const int quad = lane >> 4, l15 = lane & 15;
  const int m0 = blockIdx.x * 64;  // e-range

  f32x4 acc[4][4];
  const f32x4 fz = {0.f, 0.f, 0.f, 0.f};
#pragma unroll
  for (int i = 0; i < 4; ++i)
#pragma unroll
    for (int j = 0; j < 4; ++j) acc[i][j] = fz;

  for (int k0 = 0; k0 < CH; k0 += 32) {
    __syncthreads();
    {  // A: bf16 already, async copy. 16 rows per wave.
      const unsigned short* g = x1bf + (size_t)(m0 + wave * 16 + (lane >> 2)) * CH + k0 + (lane & 3) * 8;
      async_copy16(g, &a_lds[(wave * 16) * 32]);
    }
#pragma unroll
    for (int i = 0; i < 4; ++i) {
      int rowbase = wave * 64 + i * 16;
      const unsigned short* g = W1T + (size_t)(rowbase + (lane >> 2)) * CH + k0 + (lane & 3) * 8;
      async_copy16(g, &b_lds[rowbase * 32]);
    }
    __syncthreads();
    bf16x8 af[4];
#pragma unroll
    for (int i = 0; i < 4; ++i)
      af[i] = *(const bf16x8*)&a_lds[(i * 16 + l15) * 32 + quad * 8];
#pragma unroll
    for (int j = 0; j < 4; ++j) {
      bf16x8 bfr = *(const bf16x8*)&b_lds[(wave * 64 + j * 16 + l15) * 32 + quad * 8];
#pragma unroll
      for (int i = 0; i < 4; ++i)
        acc[i][j] = __builtin_amdgcn_mfma_f32_16x16x32_bf16(af[i], bfr, acc[i][j], 0, 0, 0);
    }
  }
#pragma unroll
  for (int i = 0; i < 4; ++i) {
    int row4 = m0 + i * 16 + quad * 4;
    float4 ec = *(const float4*)(edge_card + row4);
#pragma unroll
    for (int j = 0; j < 4; ++j) {
      int col = wave * 64 + j * 16 + l15;
      f32x4 v = acc[i][j];
      ushort4 o;
      o.x = f2bf(v[0] * ec.x);
      o.y = f2bf(v[1] * ec.y);
      o.z = f2bf(v[2] * ec.z);
      o.w = f2bf(v[3] * ec.w);
      *(ushort4*)&y1sT[(size_t)col * NE + row4] = o;
    }
  }
}

// ---------------- K5b: y1sT aux row (256 = edge_card) ----------------
__global__ void k5b_aux(const float* __restrict__ edge_card, unsigned short* __restrict__ y1sT) {
  int e = blockIdx.x * 256 + threadIdx.x;
  y1sT[(size_t)256 * NE + e] = f2bf(edge_card[e]);
}

// ---------------- MM2: B1 @ y1s (BM=128, split=4, XCD pair, dbuf) ----------
__global__ __launch_bounds__(512, 4) void mm2_kernel(const unsigned char* __restrict__ pk1,
                                                     const unsigned short* __restrict__ y1sT,
                                                     float* __restrict__ mm2p,
                                                     float* __restrict__ d0p) {
  __shared__ __align__(16) unsigned short a_lds[2][128 * 40];
  __shared__ __align__(16) unsigned short b_lds[2][272 * 32];
  const int tid = threadIdx.x;
  const int wave = tid >> 6, lane = tid & 63;
  const int quad = lane >> 4, l15 = lane & 15;
  const int wm = wave >> 2, wn = wave & 3;
  const int bid = blockIdx.x;
  const int sp = (bid >> 1) & 3;                         // XCD pair {2sp,2sp+1}
  const int m0 = (((bid >> 3) << 1) | (bid & 1)) * 128;  // node-range
  const int KS = NE / MM2_SPLIT;                         // 2048
  const int NT = KS / 32;                                // 64
  const int kbase = sp * KS;

  const int am = tid >> 2;
  const int akg = tid & 3;
  const int ajbs = akg ^ ((am >> 4) & 3);
  const int aoff = am * 40 + ajbs * 8;
  const int brow = lane >> 2;
  const int bcol = (lane & 3) * 8;

  f32x4 acc[4][4];
  const f32x4 fz = {0.f, 0.f, 0.f, 0.f};
#pragma unroll
  for (int i = 0; i < 4; ++i)
#pragma unroll
    for (int j = 0; j < 4; ++j) acc[i][j] = fz;
  float daux = 0.f;

  const unsigned char* agp = pk1 + (size_t)(m0 + am) * (NE / 8) + (kbase >> 3) + akg;
  unsigned ab_cur = agp[0];
  unsigned ab_nxt = agp[4];
  const unsigned char* agq = agp + 8;

  // prologue: stage tile 0 into buffer 0
#pragma unroll
  for (int i = 0; i < 2; ++i) {
    int rowbase = wave * 32 + i * 16;
    const unsigned short* g = y1sT + (size_t)(rowbase + brow) * NE + kbase + bcol;
    async_copy16(g, &b_lds[0][rowbase * 32]);
  }
  if (wave == 7) {
    const unsigned short* g = y1sT + (size_t)(256 + brow) * NE + kbase + bcol;
    async_copy16(g, &b_lds[0][256 * 32]);
  }
  *(uint4*)&a_lds[0][aoff] = expand8(ab_cur);
  __syncthreads();

  for (int t = 0; t < NT; ++t) {
    const int cur = t & 1;
    unsigned ab_new = 0;
    if (t + 1 < NT) {
      const int k0n = kbase + (t + 1) * 32;
#pragma unroll
      for (int i = 0; i < 2; ++i) {
        int rowbase = wave * 32 + i * 16;
        const unsigned short* g = y1sT + (size_t)(rowbase + brow) * NE + k0n + bcol;
        async_copy16(g, &b_lds[cur ^ 1][rowbase * 32]);
      }
      if (wave == 7) {
        const unsigned short* g = y1sT + (size_t)(256 + brow) * NE + k0n + bcol;
        async_copy16(g, &b_lds[cur ^ 1][256 * 32]);
      }
      *(uint4*)&a_lds[cur ^ 1][aoff] = expand8(ab_nxt);
      if (t + 2 < NT) {
        ab_new = *agq;
        agq += 4;
      }
    }
    {  // d0 partial: bits vs edge_card (aux row 256)
      bf16x8 ec8 = *(const bf16x8*)&b_lds[cur][256 * 32 + akg * 8];
      float part = 0.f;
#pragma unroll
      for (int j = 0; j < 8; ++j) {
        float ecf = __uint_as_float(((unsigned)(unsigned short)ec8[j]) << 16);
        part += ((ab_cur >> j) & 1u) ? ecf : 0.f;
      }
      daux += part;
    }
    bf16x8 af[4];
#pragma unroll
    for (int i = 0; i < 4; ++i) {
      int m = wm * 64 + i * 16 + l15;
      int jbs = quad ^ i;
      af[i] = *(const bf16x8*)&a_lds[cur][m * 40 + jbs * 8];
    }
#pragma unroll
    for (int j = 0; j < 4; ++j) {
      bf16x8 bfr = *(const bf16x8*)&b_lds[cur][(wn * 64 + j * 16 + l15) * 32 + quad * 8];
#pragma unroll
      for (int i = 0; i < 4; ++i)
        acc[i][j] = __builtin_amdgcn_mfma_f32_16x16x32_bf16(af[i], bfr, acc[i][j], 0, 0, 0);
    }
    __syncthreads();
    ab_cur = ab_nxt;
    ab_nxt = ab_new;
  }
  float* outp = mm2p + (size_t)sp * NN * CH;
#pragma unroll
  for (int i = 0; i < 4; ++i) {
    int row4 = m0 + wm * 64 + i * 16 + quad * 4;
#pragma unroll
    for (int j = 0; j < 4; ++j) {
      int col = wn * 64 + j * 16 + l15;
#pragma unroll
      for (int r = 0; r < 4; ++r) outp[(size_t)(row4 + r) * CH + col] = acc[i][j][r];
    }
  }
  __syncthreads();
  float* dred = (float*)a_lds;
  dred[tid] = daux;
  __syncthreads();
  if (tid < 128) {
    float s = dred[tid * 4] + dred[tid * 4 + 1] + dred[tid * 4 + 2] + dred[tid * 4 + 3];
    d0p[(size_t)sp * NN + m0 + tid] = s;
  }
}

// ---------------- K6: node finalize (reduce 4 partials) ----------------
__global__ void k6_node_final(const float* __restrict__ mm2p, const float* __restrict__ d0p,
                              const float* __restrict__ b10, float* __restrict__ out0) {
  int n = blockIdx.x, c = threadIdx.x;
  float s = 0.f, d = 0.f;
#pragma unroll
  for (int sp = 0; sp < MM2_SPLIT; ++sp) {
    s += mm2p[(size_t)sp * NN * CH + (size_t)n * CH + c];
    d += d0p[(size_t)sp * NN + n];
  }
  float v = s / d + b10[c];
  out0[(size_t)n * CH + c] = fmaxf(v, 0.f);
}

extern "C" void kernel_launch(void* const* d_in, const int* in_sizes, int n_in,
                              void* d_out, int out_size, void* d_ws, size_t ws_size,
                              hipStream_t stream) {
  const float* x0 = (const float*)d_in[0];
  const float* B1 = (const float*)d_in[1];
  const float* W0 = (const float*)d_in[2];
  const float* W1 = (const float*)d_in[3];
  const float* b01 = (const float*)d_in[4];
  const float* b10 = (const float*)d_in[5];
  float* out0 = (float*)d_out;
  float* out1 = out0 + (size_t)NN * CH;

  char* ws = (char*)d_ws;
  size_t off = 0;
  auto take = [&](size_t bytes) {
    void* p = ws + off;
    off += (bytes + 255) & ~(size_t)255;
    return p;
  };
  unsigned short* y0sT = (unsigned short*)take((size_t)272 * NN * 2);          // 8.9 MB
  unsigned short* y1sT = (unsigned short*)take((size_t)272 * NE * 2);          // 4.5 MB
  unsigned short* x1bf = (unsigned short*)take((size_t)NE * CH * 2);           // 4.2 MB
  float* mm1p = (float*)take((size_t)MM1_SPLIT * NE * CH * 4);                 // 67.1 MB
  float* mm2p = mm1p;  // alias: mm1p dead after K3; MM2_SPLIT*NN*CH*4 == same size
  float* node_card = (float*)take((size_t)NN * 4);
  float* edge_card = (float*)take((size_t)NE * 4);
  float* auxD = (float*)take((size_t)MM1_SPLIT * NE * 4);
  float* d0p = (float*)take((size_t)MM2_SPLIT * NN * 4);
  unsigned short* W0T = (unsigned short*)take((size_t)CH * CH * 2);
  unsigned short* W1T = (unsigned short*)take((size_t)CH * CH * 2);
  unsigned* pk1 = (unsigned*)take((size_t)NN * 256 * 4);                       // 16.8 MB packed B1
  unsigned* pk1T = (unsigned*)take((size_t)NE * 512 * 4);                      // 16.8 MB packed B1^T
  (void)ws_size; (void)in_sizes; (void)n_in; (void)out_size;

  k0_transpose_w<<<dim3(256, 2), 256, 0, stream>>>(W0, W1, W0T, W1T);
  k1_pack_card<<<NN, 256, 0, stream>>>(B1, pk1, node_card);
  k1b_bitT<<<256, 256, 0, stream>>>(pk1, pk1T);
  kcs_edge_card<<<NE / 4, 256, 0, stream>>>(pk1T, edge_card);
  k2_y0<<<NN / 64, 256, 0, stream>>>(x0, W0T, node_card, y0sT);
  k2b_aux<<<NN / 256, 256, 0, stream>>>(node_card, y0sT);
  mm1_kernel<<<512, 512, 0, stream>>>((const unsigned char*)pk1T, y0sT, mm1p, auxD);
  k3_edge_final<<<NE, 256, 0, stream>>>(mm1p, auxD, b01, out1, x1bf);
  k5_y1<<<NE / 64, 256, 0, stream>>>(x1bf, W1T, edge_card, y1sT);
  k5b_aux<<<NE / 256, 256, 0, stream>>>(edge_card, y1sT);
  mm2_kernel<<<512, 512, 0, stream>>>((const unsigned char*)pk1, y1sT, mm2p, d0p);
  k6_node_final<<<NN, 256, 0, stream>>>(mm2p, d0p, b10, out0);
}

// Round 4
// 955.995 us; speedup vs baseline: 1.2025x; 1.0188x over previous
//
// HNHN layer on MI355X (gfx950). Round 6: lean MM loops + standalone d1/d0.
// d1[e]=sum_n B1[n,e]*node_card[n] and d0[n]=sum_e B1[n,e]*edge_card[e] are
// weighted popcounts of the packed bit matrix -> tiny KE/KD0 kernels (fp32,
// more accurate than the old bf16 aux-row path). MM1/MM2 lose the in-loop
// daux (~17 VALU/iter), the aux-row staging, and the epilogue reduction.
// K2/K5 go BM=32 to double their grids (occupancy). k2b/k5b/kcs deleted.
// Pipeline:
//   K0:  W0,W1 -> bf16 transposed (W0T/W1T, [n][k])
//   K1:  pack B1 rows -> pk1[n][256 u32] + node_card = popcnt^-0.5
//   K1b: bit-transpose pk1 -> pk1T[e][512 u32]
//   KE:  edge_card[e] = popcnt(pk1T[e])^-1.5 ; d1[e] = sum node_card (masked)
//   KD0: d0[n] = sum edge_card (masked by pk1[n])
//   K2:  y0 = x0@W0 (MFMA, BM=32); epilogue y0sT[c][n] = bf16(node_card[n]*y0)
//   MM1: mm1p[sp] = B1^T-slice @ y0s (split=8, sp=XCD; BM=128; dbuf)
//   K3:  x1 = sum(p)/d1+b01; out1=relu(x1); x1bf=bf16(x1)
//   K5:  y1 = x1@W1 (MFMA, BM=32); epilogue y1sT[c][e]=bf16(edge_card[e]*y1)
//   MM2: mm2p[sp] = B1-slice @ y1s (split=4, sp=XCD pair; BM=128; dbuf)
//   K6:  out0 = relu(sum(mm2p)/d0 + b10)
#include <hip/hip_runtime.h>
#include <stdint.h>

#define NN 16384
#define NE 8192
#define CH 256
#define MM1_SPLIT 8
#define MM2_SPLIT 4

typedef __attribute__((ext_vector_type(8))) short bf16x8;
typedef __attribute__((ext_vector_type(4))) float f32x4;

__device__ __forceinline__ unsigned short f2bf(float f) {  // RNE fp32->bf16
  unsigned u = __float_as_uint(f);
  u += 0x7FFFu + ((u >> 16) & 1u);
  return (unsigned short)(u >> 16);
}
__device__ __forceinline__ void async_copy16(const void* gptr, void* lptr) {
  __builtin_amdgcn_global_load_lds((const __attribute__((address_space(1))) unsigned int*)gptr,
                                   (__attribute__((address_space(3))) unsigned int*)lptr,
                                   16, 0, 0);
}
// expand 8 A-bits -> 8 bf16 {0,1} packed in uint4 (2 bf16 per u32)
__device__ __forceinline__ uint4 expand8(unsigned byte) {
  uint4 aw;
#pragma unroll
  for (int j = 0; j < 4; ++j) {
    unsigned lo = (byte >> (2 * j)) & 1u;
    unsigned hi = (byte >> (2 * j + 1)) & 1u;
    ((unsigned*)&aw)[j] = lo * 0x3F80u + hi * 0x3F800000u;
  }
  return aw;
}

// LSB-first 32x32 bit transpose: result x'[k] bit j == input x[j] bit k.
__device__ __forceinline__ void transpose32(unsigned* x) {
  const unsigned masks[5] = {0x0000FFFFu, 0x00FF00FFu, 0x0F0F0F0Fu, 0x33333333u, 0x55555555u};
#pragma unroll
  for (int jj = 0; jj < 5; ++jj) {
    const int j = 16 >> jj;
    const unsigned m = masks[jj];
#pragma unroll
    for (int k = 0; k < 32; ++k) {
      if ((k & j) == 0) {
        unsigned t = ((x[k] >> j) ^ x[k + j]) & m;
        x[k] ^= (t << j);
        x[k + j] ^= t;
      }
    }
  }
}

// ---------------- K0: weight transpose to bf16 ----------------
__global__ void k0_transpose_w(const float* __restrict__ W0, const float* __restrict__ W1,
                               unsigned short* __restrict__ W0T, unsigned short* __restrict__ W1T) {
  const float* W = blockIdx.y ? W1 : W0;
  unsigned short* WT = blockIdx.y ? W1T : W0T;
  int n = blockIdx.x;
  int k = threadIdx.x;
  WT[n * CH + k] = f2bf(W[k * CH + n]);
}

// ---------------- K1: pack B1 row to bits + node_card ----------------
__global__ void k1_pack_card(const float* __restrict__ B1, unsigned* __restrict__ pk1,
                             float* __restrict__ node_card) {
  int n = blockIdx.x;
  int t = threadIdx.x;
  const float4* p = (const float4*)(B1 + (size_t)n * NE + t * 32);
  unsigned w = 0;
#pragma unroll
  for (int jj = 0; jj < 8; ++jj) {
    float4 v = p[jj];
    w |= ((__float_as_uint(v.x) >> 23) & 1u) << (4 * jj);
    w |= ((__float_as_uint(v.y) >> 23) & 1u) << (4 * jj + 1);
    w |= ((__float_as_uint(v.z) >> 23) & 1u) << (4 * jj + 2);
    w |= ((__float_as_uint(v.w) >> 23) & 1u) << (4 * jj + 3);
  }
  pk1[(size_t)n * 256 + t] = w;
  int s = __popc(w);
  __shared__ int red[4];
#pragma unroll
  for (int off = 32; off; off >>= 1) s += __shfl_down(s, off, 64);
  if ((t & 63) == 0) red[t >> 6] = s;
  __syncthreads();
  if (t == 0) {
    float tot = (float)(red[0] + red[1] + red[2] + red[3]);
    node_card[n] = rsqrtf(tot);
  }
}

// ---------------- K1b: bit transpose pk1 -> pk1T ----------------
__global__ __launch_bounds__(256) void k1b_bitT(const unsigned* __restrict__ pk1,
                                                unsigned* __restrict__ pk1T) {
  int bw = blockIdx.x & 127;   // e-word pair: words 2bw, 2bw+1 (e-range 64)
  int half = blockIdx.x >> 7;  // which half of the 512 n-tiles
  int t = threadIdx.x;
  int nt = half * 256 + t;     // n-word tile 0..511
  unsigned x0[32], x1[32];
#pragma unroll
  for (int r = 0; r < 32; ++r) {
    uint2 v = *(const uint2*)&pk1[(size_t)(nt * 32 + r) * 256 + 2 * bw];
    x0[r] = v.x;
    x1[r] = v.y;
  }
  transpose32(x0);
  transpose32(x1);
  int e0 = bw * 64;
#pragma unroll
  for (int c = 0; c < 32; ++c) {
    pk1T[(size_t)(e0 + c) * 512 + nt] = x0[c];
    pk1T[(size_t)(e0 + 32 + c) * 512 + nt] = x1[c];
  }
}

// ---------------- KE: edge_card + d1 from pk1T (fp32 weighted popcount) ----
// Block = 4 e-rows. Thread t owns words {t, t+256}; node_card chunk reads are
// block-exclusive (64 KB/block total = one full pass, L2-resident).
__global__ __launch_bounds__(256) void ke_edge(const unsigned* __restrict__ pk1T,
                                               const float* __restrict__ node_card,
                                               float* __restrict__ edge_card,
                                               float* __restrict__ d1) {
  const int t = threadIdx.x;
  const int e0 = blockIdx.x * 4;
  unsigned w[4][2];
#pragma unroll
  for (int r = 0; r < 4; ++r) {
    w[r][0] = pk1T[(size_t)(e0 + r) * 512 + t];
    w[r][1] = pk1T[(size_t)(e0 + r) * 512 + 256 + t];
  }
  float wsum[4] = {0.f, 0.f, 0.f, 0.f};
  int cnt[4];
#pragma unroll
  for (int r = 0; r < 4; ++r) cnt[r] = __popc(w[r][0]) + __popc(w[r][1]);
  const float4* nc0 = (const float4*)(node_card + (size_t)t * 32);
  const float4* nc1 = (const float4*)(node_card + ((size_t)t + 256) * 32);
#pragma unroll
  for (int h = 0; h < 2; ++h) {
    const float4* ncp = h ? nc1 : nc0;
#pragma unroll
    for (int q = 0; q < 8; ++q) {
      float4 v = ncp[q];
#pragma unroll
      for (int r = 0; r < 4; ++r) {
        unsigned ww = w[r][h];
        wsum[r] += ((ww >> (4 * q)) & 1u) ? v.x : 0.f;
        wsum[r] += ((ww >> (4 * q + 1)) & 1u) ? v.y : 0.f;
        wsum[r] += ((ww >> (4 * q + 2)) & 1u) ? v.z : 0.f;
        wsum[r] += ((ww >> (4 * q + 3)) & 1u) ? v.w : 0.f;
      }
    }
  }
#pragma unroll
  for (int off = 32; off; off >>= 1)
#pragma unroll
    for (int r = 0; r < 4; ++r) {
      wsum[r] += __shfl_down(wsum[r], off, 64);
      cnt[r] += __shfl_down(cnt[r], off, 64);
    }
  __shared__ float redW[4][4];
  __shared__ int redC[4][4];
  int wave = t >> 6, lane = t & 63;
  if (lane == 0)
#pragma unroll
    for (int r = 0; r < 4; ++r) {
      redW[wave][r] = wsum[r];
      redC[wave][r] = cnt[r];
    }
  __syncthreads();
  if (t < 4) {
    float s = redW[0][t] + redW[1][t] + redW[2][t] + redW[3][t];
    float c = (float)(redC[0][t] + redC[1][t] + redC[2][t] + redC[3][t]);
    d1[e0 + t] = s;
    edge_card[e0 + t] = 1.0f / (c * sqrtf(c));  // c^-1.5
  }
}

// ---------------- KD0: d0 from pk1 (weighted popcount by edge_card) --------
__global__ __launch_bounds__(256) void kd0_node(const unsigned* __restrict__ pk1,
                                                const float* __restrict__ edge_card,
                                                float* __restrict__ d0) {
  const int t = threadIdx.x;
  const int n0 = blockIdx.x * 4;
  unsigned w[4];
#pragma unroll
  for (int r = 0; r < 4; ++r) w[r] = pk1[(size_t)(n0 + r) * 256 + t];
  float wsum[4] = {0.f, 0.f, 0.f, 0.f};
  const float4* ecp = (const float4*)(edge_card + (size_t)t * 32);
#pragma unroll
  for (int q = 0; q < 8; ++q) {
    float4 v = ecp[q];
#pragma unroll
    for (int r = 0; r < 4; ++r) {
      unsigned ww = w[r];
      wsum[r] += ((ww >> (4 * q)) & 1u) ? v.x : 0.f;
      wsum[r] += ((ww >> (4 * q + 1)) & 1u) ? v.y : 0.f;
      wsum[r] += ((ww >> (4 * q + 2)) & 1u) ? v.z : 0.f;
      wsum[r] += ((ww >> (4 * q + 3)) & 1u) ? v.w : 0.f;
    }
  }
#pragma unroll
  for (int off = 32; off; off >>= 1)
#pragma unroll
    for (int r = 0; r < 4; ++r) wsum[r] += __shfl_down(wsum[r], off, 64);
  __shared__ float redW[4][4];
  int wave = t >> 6, lane = t & 63;
  if (lane == 0)
#pragma unroll
    for (int r = 0; r < 4; ++r) redW[wave][r] = wsum[r];
  __syncthreads();
  if (t < 4) d0[n0 + t] = redW[0][t] + redW[1][t] + redW[2][t] + redW[3][t];
}

// ---------------- K2: y0 GEMM (BM=32) + scaled transpose epilogue ----------
__global__ __launch_bounds__(256) void k2_y0(const float* __restrict__ X0,
                                             const unsigned short* __restrict__ W0T,
                                             const float* __restrict__ node_card,
                                             unsigned short* __restrict__ y0sT) {
  __shared__ __align__(16) unsigned short a_lds[32 * 32];
  __shared__ __align__(16) unsigned short b_lds[256 * 32];
  const int tid = threadIdx.x;
  const int wave = tid >> 6, lane = tid & 63;
  const int quad = lane >> 4, l15 = lane & 15;
  const int m0 = blockIdx.x * 32;
  const int ar = tid >> 3, ac = (tid & 7) * 4;

  f32x4 acc[2][4];
  const f32x4 fz = {0.f, 0.f, 0.f, 0.f};
#pragma unroll
  for (int i = 0; i < 2; ++i)
#pragma unroll
    for (int j = 0; j < 4; ++j) acc[i][j] = fz;

  for (int k0 = 0; k0 < CH; k0 += 32) {
    __syncthreads();
    {
      float4 v = *(const float4*)(X0 + (size_t)(m0 + ar) * CH + k0 + ac);
      uint2 w;
      w.x = ((unsigned)f2bf(v.x)) | ((unsigned)f2bf(v.y) << 16);
      w.y = ((unsigned)f2bf(v.z)) | ((unsigned)f2bf(v.w) << 16);
      *(uint2*)&a_lds[ar * 32 + ac] = w;
    }
#pragma unroll
    for (int i = 0; i < 4; ++i) {
      int rowbase = wave * 64 + i * 16;
      const unsigned short* g = W0T + (size_t)(rowbase + (lane >> 2)) * CH + k0 + (lane & 3) * 8;
      async_copy16(g, &b_lds[rowbase * 32]);
    }
    __syncthreads();
    bf16x8 af[2];
#pragma unroll
    for (int i = 0; i < 2; ++i)
      af[i] = *(const bf16x8*)&a_lds[(i * 16 + l15) * 32 + quad * 8];
#pragma unroll
    for (int j = 0; j < 4; ++j) {
      bf16x8 bfr = *(const bf16x8*)&b_lds[(wave * 64 + j * 16 + l15) * 32 + quad * 8];
#pragma unroll
      for (int i = 0; i < 2; ++i)
        acc[i][j] = __builtin_amdgcn_mfma_f32_16x16x32_bf16(af[i], bfr, acc[i][j], 0, 0, 0);
    }
  }
#pragma unroll
  for (int i = 0; i < 2; ++i) {
    int row4 = m0 + i * 16 + quad * 4;
    float4 nc = *(const float4*)(node_card + row4);
#pragma unroll
    for (int j = 0; j < 4; ++j) {
      int col = wave * 64 + j * 16 + l15;
      f32x4 v = acc[i][j];
      ushort4 o;
      o.x = f2bf(v[0] * nc.x);
      o.y = f2bf(v[1] * nc.y);
      o.z = f2bf(v[2] * nc.z);
      o.w = f2bf(v[3] * nc.w);
      *(ushort4*)&y0sT[(size_t)col * NN + row4] = o;
    }
  }
}

// ---------------- MM1: B1^T @ y0s (BM=128, split=8, XCD-pinned, dbuf) ------
__global__ __launch_bounds__(512, 4) void mm1_kernel(const unsigned char* __restrict__ pk1T,
                                                     const unsigned short* __restrict__ y0sT,
                                                     float* __restrict__ mm1p) {
  __shared__ __align__(16) unsigned short a_lds[2][128 * 40];
  __shared__ __align__(16) unsigned short b_lds[2][256 * 32];
  const int tid = threadIdx.x;
  const int wave = tid >> 6, lane = tid & 63;
  const int quad = lane >> 4, l15 = lane & 15;
  const int wm = wave >> 2, wn = wave & 3;
  const int bid = blockIdx.x;
  const int sp = bid & 7;            // XCD-pinned K-split
  const int m0 = (bid >> 3) * 128;   // e-range
  const int KS = NN / MM1_SPLIT;     // 2048
  const int NT = KS / 32;            // 64
  const int kbase = sp * KS;

  const int am = tid >> 2;                 // e-row within tile (0..127)
  const int akg = tid & 3;                 // logical k-group (8 bf16 = 1 byte)
  const int ajbs = akg ^ ((am >> 4) & 3);  // swizzled physical group
  const int aoff = am * 40 + ajbs * 8;
  const int brow = lane >> 2;
  const int bcol = (lane & 3) * 8;

  f32x4 acc[4][4];
  const f32x4 fz = {0.f, 0.f, 0.f, 0.f};
#pragma unroll
  for (int i = 0; i < 4; ++i)
#pragma unroll
    for (int j = 0; j < 4; ++j) acc[i][j] = fz;

  const unsigned char* agp = pk1T + (size_t)(m0 + am) * (NN / 8) + (kbase >> 3) + akg;
  unsigned ab_cur = agp[0];  // byte for tile 0
  unsigned ab_nxt = agp[4];  // byte for tile 1
  const unsigned char* agq = agp + 8;

  // prologue: stage tile 0 into buffer 0
#pragma unroll
  for (int i = 0; i < 2; ++i) {
    int rowbase = wave * 32 + i * 16;
    const unsigned short* g = y0sT + (size_t)(rowbase + brow) * NN + kbase + bcol;
    async_copy16(g, &b_lds[0][rowbase * 32]);
  }
  *(uint4*)&a_lds[0][aoff] = expand8(ab_cur);
  __syncthreads();

  for (int t = 0; t < NT; ++t) {
    const int cur = t & 1;
    unsigned ab_new = 0;
    if (t + 1 < NT) {  // stage tile t+1 into buffer cur^1 (uniform branch)
      const int k0n = kbase + (t + 1) * 32;
#pragma unroll
      for (int i = 0; i < 2; ++i) {
        int rowbase = wave * 32 + i * 16;
        const unsigned short* g = y0sT + (size_t)(rowbase + brow) * NN + k0n + bcol;
        async_copy16(g, &b_lds[cur ^ 1][rowbase * 32]);
      }
      *(uint4*)&a_lds[cur ^ 1][aoff] = expand8(ab_nxt);
      if (t + 2 < NT) {
        ab_new = *agq;
        agq += 4;
      }
    }
    bf16x8 af[4];
#pragma unroll
    for (int i = 0; i < 4; ++i) {
      int m = wm * 64 + i * 16 + l15;
      int jbs = quad ^ ((m >> 4) & 3);
      af[i] = *(const bf16x8*)&a_lds[cur][m * 40 + jbs * 8];
    }
#pragma unroll
    for (int j = 0; j < 4; ++j) {
      bf16x8 bfr = *(const bf16x8*)&b_lds[cur][(wn * 64 + j * 16 + l15) * 32 + quad * 8];
#pragma unroll
      for (int i = 0; i < 4; ++i)
        acc[i][j] = __builtin_amdgcn_mfma_f32_16x16x32_bf16(af[i], bfr, acc[i][j], 0, 0, 0);
    }
    __syncthreads();  // drains vmcnt (tile t+1 B copies) + lgkm; nxt ready
    ab_cur = ab_nxt;
    ab_nxt = ab_new;
  }
  float* outp = mm1p + (size_t)sp * NE * CH;
#pragma unroll
  for (int i = 0; i < 4; ++i) {
    int row4 = m0 + wm * 64 + i * 16 + quad * 4;
#pragma unroll
    for (int j = 0; j < 4; ++j) {
      int col = wn * 64 + j * 16 + l15;
#pragma unroll
      for (int r = 0; r < 4; ++r) outp[(size_t)(row4 + r) * CH + col] = acc[i][j][r];
    }
  }
}

// ---------------- K3: edge finalize (reduce 8 partials, /d1) ----------------
__global__ void k3_edge_final(const float* __restrict__ mm1p, const float* __restrict__ d1,
                              const float* __restrict__ b01,
                              float* __restrict__ out1, unsigned short* __restrict__ x1bf) {
  int e = blockIdx.x, c = threadIdx.x;
  float p = 0.f;
#pragma unroll
  for (int sp = 0; sp < MM1_SPLIT; ++sp)
    p += mm1p[(size_t)sp * NE * CH + (size_t)e * CH + c];
  float x1 = p / d1[e] + b01[c];
  out1[(size_t)e * CH + c] = fmaxf(x1, 0.f);
  x1bf[(size_t)e * CH + c] = f2bf(x1);
}

// ---------------- K5: y1 GEMM (BM=32) + scaled transpose epilogue ----------
__global__ __launch_bounds__(256) void k5_y1(const unsigned short* __restrict__ x1bf,
                                             const unsigned short* __restrict__ W1T,
                                             const float* __restrict__ edge_card,
                                             unsigned short* __restrict__ y1sT) {
  __shared__ __align__(16) unsigned short a_lds[32 * 32];
  __shared__ __align__(16) unsigned short b_lds[256 * 32];
  const int tid = threadIdx.x;
  const int wave = tid >> 6, lane = tid & 63;
  const int quad = lane >> 4, l15 = lane & 15;
  const int m0 = blockIdx.x * 32;  // e-range

  f32x4 acc[2][4];
  const f32x4 fz = {0.f, 0.f, 0.f, 0.f};
#pragma unroll
  for (int i = 0; i < 2; ++i)
#pragma unroll
    for (int j = 0; j < 4; ++j) acc[i][j] = fz;

  for (int k0 = 0; k0 < CH; k0 += 32) {
    __syncthreads();
    if (wave < 2) {  // A: 16 rows per wave, async copy
      const unsigned short* g = x1bf + (size_t)(m0 + wave * 16 + (lane >> 2)) * CH + k0 + (lane & 3) * 8;
      async_copy16(g, &a_lds[(wave * 16) * 32]);
    }
#pragma unroll
    for (int i = 0; i < 4; ++i) {
      int rowbase = wave * 64 + i * 16;
      const unsigned short* g = W1T + (size_t)(rowbase + (lane >> 2)) * CH + k0 + (lane & 3) * 8;
      async_copy16(g, &b_lds[rowbase * 32]);
    }
    __syncthreads();
    bf16x8 af[2];
#pragma unroll
    for (int i = 0; i < 2; ++i)
      af[i] = *(const bf16x8*)&a_lds[(i * 16 + l15) * 32 + quad * 8];
#pragma unroll
    for (int j = 0; j < 4; ++j) {
      bf16x8 bfr = *(const bf16x8*)&b_lds[(wave * 64 + j * 16 + l15) * 32 + quad * 8];
#pragma unroll
      for (int i = 0; i < 2; ++i)
        acc[i][j] = __builtin_amdgcn_mfma_f32_16x16x32_bf16(af[i], bfr, acc[i][j], 0, 0, 0);
    }
  }
#pragma unroll
  for (int i = 0; i < 2; ++i) {
    int row4 = m0 + i * 16 + quad * 4;
    float4 ec = *(const float4*)(edge_card + row4);
#pragma unroll
    for (int j = 0; j < 4; ++j) {
      int col = wave * 64 + j * 16 + l15;
      f32x4 v = acc[i][j];
      ushort4 o;
      o.x = f2bf(v[0] * ec.x);
      o.y = f2bf(v[1] * ec.y);
      o.z = f2bf(v[2] * ec.z);
      o.w = f2bf(v[3] * ec.w);
      *(ushort4*)&y1sT[(size_t)col * NE + row4] = o;
    }
  }
}

// ---------------- MM2: B1 @ y1s (BM=128, split=4, XCD pair, dbuf) ----------
__global__ __launch_bounds__(512, 4) void mm2_kernel(const unsigned char* __restrict__ pk1,
                                                     const unsigned short* __restrict__ y1sT,
                                                     float* __restrict__ mm2p) {
  __shared__ __align__(16) unsigned short a_lds[2][128 * 40];
  __shared__ __align__(16) unsigned short b_lds[2][256 * 32];
  const int tid = threadIdx.x;
  const int wave = tid >> 6, lane = tid & 63;
  const int quad = lane >> 4, l15 = lane & 15;
  const int wm = wave >> 2, wn = wave & 3;
  const int bid = blockIdx.x;
  const int sp = (bid >> 1) & 3;                         // XCD pair {2sp,2sp+1}
  const int m0 = (((bid >> 3) << 1) | (bid & 1)) * 128;  // node-range
  const int KS = NE / MM2_SPLIT;                         // 2048
  const int NT = KS / 32;                                // 64
  const int kbase = sp * KS;

  const int am = tid >> 2;
  const int akg = tid & 3;
  const int ajbs = akg ^ ((am >> 4) & 3);
  const int aoff = am * 40 + ajbs * 8;
  const int brow = lane >> 2;
  const int bcol = (lane & 3) * 8;

  f32x4 acc[4][4];
  const f32x4 fz = {0.f, 0.f, 0.f, 0.f};
#pragma unroll
  for (int i = 0; i < 4; ++i)
#pragma unroll
    for (int j = 0; j < 4; ++j) acc[i][j] = fz;

  const unsigned char* agp = pk1 + (size_t)(m0 + am) * (NE / 8) + (kbase >> 3) + akg;
  unsigned ab_cur = agp[0];
  unsigned ab_nxt = agp[4];
  const unsigned char* agq = agp + 8;

  // prologue: stage tile 0 into buffer 0
#pragma unroll
  for (int i = 0; i < 2; ++i) {
    int rowbase = wave * 32 + i * 16;
    const unsigned short* g = y1sT + (size_t)(rowbase + brow) * NE + kbase + bcol;
    async_copy16(g, &b_lds[0][rowbase * 32]);
  }
  *(uint4*)&a_lds[0][aoff] = expand8(ab_cur);
  __syncthreads();

  for (int t = 0; t < NT; ++t) {
    const int cur = t & 1;
    unsigned ab_new = 0;
    if (t + 1 < NT) {
      const int k0n = kbase + (t + 1) * 32;
#pragma unroll
      for (int i = 0; i < 2; ++i) {
        int rowbase = wave * 32 + i * 16;
        const unsigned short* g = y1sT + (size_t)(rowbase + brow) * NE + k0n + bcol;
        async_copy16(g, &b_lds[cur ^ 1][rowbase * 32]);
      }
      *(uint4*)&a_lds[cur ^ 1][aoff] = expand8(ab_nxt);
      if (t + 2 < NT) {
        ab_new = *agq;
        agq += 4;
      }
    }
    bf16x8 af[4];
#pragma unroll
    for (int i = 0; i < 4; ++i) {
      int m = wm * 64 + i * 16 + l15;
      int jbs = quad ^ ((m >> 4) & 3);
      af[i] = *(const bf16x8*)&a_lds[cur][m * 40 + jbs * 8];
    }
#pragma unroll
    for (int j = 0; j < 4; ++j) {
      bf16x8 bfr = *(const bf16x8*)&b_lds[cur][(wn * 64 + j * 16 + l15) * 32 + quad * 8];
#pragma unroll
      for (int i = 0; i < 4; ++i)
        acc[i][j] = __builtin_amdgcn_mfma_f32_16x16x32_bf16(af[i], bfr, acc[i][j], 0, 0, 0);
    }
    __syncthreads();
    ab_cur = ab_nxt;
    ab_nxt = ab_new;
  }
  float* outp = mm2p + (size_t)sp * NN * CH;
#pragma unroll
  for (int i = 0; i < 4; ++i) {
    int row4 = m0 + wm * 64 + i * 16 + quad * 4;
#pragma unroll
    for (int j = 0; j < 4; ++j) {
      int col = wn * 64 + j * 16 + l15;
#pragma unroll
      for (int r = 0; r < 4; ++r) outp[(size_t)(row4 + r) * CH + col] = acc[i][j][r];
    }
  }
}

// ---------------- K6: node finalize (reduce 4 partials, /d0) ----------------
__global__ void k6_node_final(const float* __restrict__ mm2p, const float* __restrict__ d0,
                              const float* __restrict__ b10, float* __restrict__ out0) {
  int n = blockIdx.x, c = threadIdx.x;
  float s = 0.f;
#pragma unroll
  for (int sp = 0; sp < MM2_SPLIT; ++sp)
    s += mm2p[(size_t)sp * NN * CH + (size_t)n * CH + c];
  float v = s / d0[n] + b10[c];
  out0[(size_t)n * CH + c] = fmaxf(v, 0.f);
}

extern "C" void kernel_launch(void* const* d_in, const int* in_sizes, int n_in,
                              void* d_out, int out_size, void* d_ws, size_t ws_size,
                              hipStream_t stream) {
  const float* x0 = (const float*)d_in[0];
  const float* B1 = (const float*)d_in[1];
  const float* W0 = (const float*)d_in[2];
  const float* W1 = (const float*)d_in[3];
  const float* b01 = (const float*)d_in[4];
  const float* b10 = (const float*)d_in[5];
  float* out0 = (float*)d_out;
  float* out1 = out0 + (size_t)NN * CH;

  char* ws = (char*)d_ws;
  size_t off = 0;
  auto take = [&](size_t bytes) {
    void* p = ws + off;
    off += (bytes + 255) & ~(size_t)255;
    return p;
  };
  unsigned short* y0sT = (unsigned short*)take((size_t)256 * NN * 2);          // 8.4 MB
  unsigned short* y1sT = (unsigned short*)take((size_t)256 * NE * 2);          // 4.2 MB
  unsigned short* x1bf = (unsigned short*)take((size_t)NE * CH * 2);           // 4.2 MB
  float* mm1p = (float*)take((size_t)MM1_SPLIT * NE * CH * 4);                 // 67.1 MB
  float* mm2p = mm1p;  // alias: mm1p dead after K3; MM2_SPLIT*NN*CH*4 == same size
  float* node_card = (float*)take((size_t)NN * 4);
  float* edge_card = (float*)take((size_t)NE * 4);
  float* d1 = (float*)take((size_t)NE * 4);
  float* d0 = (float*)take((size_t)NN * 4);
  unsigned short* W0T = (unsigned short*)take((size_t)CH * CH * 2);
  unsigned short* W1T = (unsigned short*)take((size_t)CH * CH * 2);
  unsigned* pk1 = (unsigned*)take((size_t)NN * 256 * 4);                       // 16.8 MB packed B1
  unsigned* pk1T = (unsigned*)take((size_t)NE * 512 * 4);                      // 16.8 MB packed B1^T
  (void)ws_size; (void)in_sizes; (void)n_in; (void)out_size;

  k0_transpose_w<<<dim3(256, 2), 256, 0, stream>>>(W0, W1, W0T, W1T);
  k1_pack_card<<<NN, 256, 0, stream>>>(B1, pk1, node_card);
  k1b_bitT<<<256, 256, 0, stream>>>(pk1, pk1T);
  ke_edge<<<NE / 4, 256, 0, stream>>>(pk1T, node_card, edge_card, d1);
  kd0_node<<<NN / 4, 256, 0, stream>>>(pk1, edge_card, d0);
  k2_y0<<<NN / 32, 256, 0, stream>>>(x0, W0T, node_card, y0sT);
  mm1_kernel<<<512, 512, 0, stream>>>((const unsigned char*)pk1T, y0sT, mm1p);
  k3_edge_final<<<NE, 256, 0, stream>>>(mm1p, d1, b01, out1, x1bf);
  k5_y1<<<NE / 32, 256, 0, stream>>>(x1bf, W1T, edge_card, y1sT);
  mm2_kernel<<<512, 512, 0, stream>>>((const unsigned char*)pk1, y1sT, mm2p);
  k6_node_final<<<NN, 256, 0, stream>>>(mm2p, d0, b10, out0);
}